// Round 2
// baseline (2338.004 us; speedup 1.0000x reference)
//
#include <hip/hip_runtime.h>

#define F 128
#define NB 20

__device__ __forceinline__ float silu_f(float x) {
    return x * (1.0f / (1.0f + __expf(-x)));
}

// Accumulate acc[R] += X[r0+r, :] @ W[:, j] for a 128-wide layer.
// X rows are read with lane-uniform addresses (scalar loads, SMEM pipe);
// W is read coalesced (each element once per block). R=16 rows/block
// amortizes the weight stream to 64KB/block.
template<int R>
__device__ __forceinline__ void gemm_acc(
    const float* __restrict__ X, const float* __restrict__ W,
    int r0, int rows, int j, float* acc)
{
    const float4* __restrict__ X4 = (const float4*)X;
    int rbase[R];
#pragma unroll
    for (int r = 0; r < R; ++r) {
        int rr = r0 + r;
        rbase[r] = (rr < rows ? rr : rows - 1) * 32;  // clamp tail rows (loads only)
    }
#pragma unroll 2
    for (int k4 = 0; k4 < 32; ++k4) {
        const int k = k4 * 4;
        const float w0 = W[(k + 0) * F + j];
        const float w1 = W[(k + 1) * F + j];
        const float w2 = W[(k + 2) * F + j];
        const float w3 = W[(k + 3) * F + j];
#pragma unroll
        for (int r = 0; r < R; ++r) {
            const float4 xv = X4[rbase[r] + k4];
            acc[r] = fmaf(xv.x, w0, acc[r]);
            acc[r] = fmaf(xv.y, w1, acc[r]);
            acc[r] = fmaf(xv.z, w2, acc[r]);
            acc[r] = fmaf(xv.w, w3, acc[r]);
        }
    }
}

// Y = act(X @ W (+ b)) for a [rows,128] x [128,128] layer.
template<bool SILU, bool BIAS>
__global__ __launch_bounds__(128) void gemm128_kernel(
    const float* __restrict__ X, const float* __restrict__ W,
    const float* __restrict__ b, float* __restrict__ Y, int rows)
{
    constexpr int R = 16;
    const int j = threadIdx.x;
    const int r0 = blockIdx.x * R;
    float acc[R];
    const float bj = BIAS ? b[j] : 0.0f;
#pragma unroll
    for (int r = 0; r < R; ++r) acc[r] = bj;
    gemm_acc<R>(X, W, r0, rows, j, acc);
#pragma unroll
    for (int r = 0; r < R; ++r) {
        const int row = r0 + r;
        if (row < rows) {
            float v = acc[r];
            if (SILU) v = silu_f(v);
            Y[(size_t)row * F + j] = v;
        }
    }
}

// ---------------- CSR build (edges grouped by src) ----------------

__global__ void zero_counts_kernel(int* __restrict__ counts, int N) {
    const int stride = gridDim.x * blockDim.x;
    for (int i = blockIdx.x * blockDim.x + threadIdx.x; i < N; i += stride)
        counts[i] = 0;
}

__global__ void csr_count_kernel(const int* __restrict__ src,
                                 int* __restrict__ counts, int E) {
    const int stride = gridDim.x * blockDim.x;
    for (int e = blockIdx.x * blockDim.x + threadIdx.x; e < E; e += stride)
        atomicAdd(&counts[src[e]], 1);
}

// Single-block exclusive scan over counts[N] -> offsets[N+1], cursor[N].
__global__ __launch_bounds__(1024) void csr_scan_kernel(
    const int* __restrict__ counts, int* __restrict__ offsets,
    int* __restrict__ cursor, int N)
{
    constexpr int T = 1024;
    const int t = threadIdx.x;
    const int per = (N + T - 1) / T;
    const int base = t * per;
    int lsum = 0;
    for (int i = 0; i < per; ++i) {
        int idx = base + i;
        if (idx < N) lsum += counts[idx];
    }
    __shared__ int s[T];
    s[t] = lsum;
    __syncthreads();
    for (int off = 1; off < T; off <<= 1) {
        int v = (t >= off) ? s[t - off] : 0;
        __syncthreads();
        s[t] += v;
        __syncthreads();
    }
    int run = s[t] - lsum;  // exclusive prefix
    for (int i = 0; i < per; ++i) {
        int idx = base + i;
        if (idx < N) {
            offsets[idx] = run;
            cursor[idx] = run;
            run += counts[idx];
        }
    }
    if (t == T - 1) offsets[N] = run;
}

__global__ void csr_perm_kernel(const int* __restrict__ src,
                                int* __restrict__ cursor,
                                int* __restrict__ perm, int E) {
    const int stride = gridDim.x * blockDim.x;
    for (int e = blockIdx.x * blockDim.x + threadIdx.x; e < E; e += stride) {
        int pos = atomicAdd(&cursor[src[e]], 1);
        perm[pos] = e;
    }
}

// ---------------- edge kernels (no atomics) ----------------

// inv_msg[e] = (dist_edge[e]@emp_W + emp_b) * h[src] * h[dst]
__global__ __launch_bounds__(256) void edge_inv_kernel(
    const float* __restrict__ dist_edge, const float* __restrict__ emp_W,
    const float* __restrict__ emp_b, const float* __restrict__ h,
    const int* __restrict__ src, const int* __restrict__ dst,
    float* __restrict__ inv_msg, int E)
{
    const int t = blockIdx.x * 256 + threadIdx.x;
    const int e = t >> 7;
    const int j = t & 127;
    if (e >= E) return;
    float acc = emp_b[j];
#pragma unroll
    for (int k = 0; k < NB; ++k)
        acc = fmaf(dist_edge[(size_t)e * NB + k], emp_W[k * F + j], acc);
    const int s = src[e];
    const int d = dst[e];
    inv_msg[(size_t)e * F + j] = acc * h[(size_t)s * F + j] * h[(size_t)d * F + j];
}

// ---------------- per-node register gathers ----------------

// atom_new[n] = atom[n] + sum_{e in CSR[n]} inv_msg[e]
__global__ __launch_bounds__(128) void gather_inv_kernel(
    const float* __restrict__ inv_msg, const int* __restrict__ offsets,
    const int* __restrict__ perm, const float* __restrict__ atom,
    float* __restrict__ atom_new, int N)
{
    const int n = blockIdx.x;
    if (n >= N) return;
    const int j = threadIdx.x;
    const int p1 = offsets[n + 1];
    float acc = 0.0f;
    for (int p = offsets[n]; p < p1; ++p) {
        const int e = perm[p];
        acc += inv_msg[(size_t)e * F + j];
    }
    atom_new[(size_t)n * F + j] = atom[(size_t)n * F + j] + acc;
}

// agg1[n,d,j] = sum_{e in CSR[n]} eqm[e,j]*disp_edge[e,d];
// out_force = force + agg1  (fused)
__global__ __launch_bounds__(128) void gather_eq1_kernel(
    const float* __restrict__ eqm, const float* __restrict__ disp_edge,
    const int* __restrict__ offsets, const int* __restrict__ perm,
    const float* __restrict__ force, float* __restrict__ agg1,
    float* __restrict__ out_force, int N)
{
    const int n = blockIdx.x;
    if (n >= N) return;
    const int j = threadIdx.x;
    const int p1 = offsets[n + 1];
    float a0 = 0.0f, a1 = 0.0f, a2 = 0.0f;
    for (int p = offsets[n]; p < p1; ++p) {
        const int e = perm[p];
        const float m = eqm[(size_t)e * F + j];
        const float d0 = disp_edge[(size_t)e * 3 + 0];
        const float d1 = disp_edge[(size_t)e * 3 + 1];
        const float d2 = disp_edge[(size_t)e * 3 + 2];
        a0 = fmaf(m, d0, a0);
        a1 = fmaf(m, d1, a1);
        a2 = fmaf(m, d2, a2);
    }
    const size_t b = (size_t)n * 3 * F + j;
    agg1[b]         = a0;
    agg1[b + F]     = a1;
    agg1[b + 2 * F] = a2;
    out_force[b]         = force[b] + a0;
    out_force[b + F]     = force[b + F] + a1;
    out_force[b + 2 * F] = force[b + 2 * F] + a2;
}

// out_disp[n,d,j] = disp_node[n,d,j] + sum_{e in CSR[n]} eqm[e,j]*disp_node[dst[e],d,j]
__global__ __launch_bounds__(128) void gather_eq2_kernel(
    const float* __restrict__ eqm, const float* __restrict__ disp_node,
    const int* __restrict__ dst, const int* __restrict__ offsets,
    const int* __restrict__ perm, float* __restrict__ out_disp, int N)
{
    const int n = blockIdx.x;
    if (n >= N) return;
    const int j = threadIdx.x;
    const int p1 = offsets[n + 1];
    float a0 = 0.0f, a1 = 0.0f, a2 = 0.0f;
    for (int p = offsets[n]; p < p1; ++p) {
        const int e = perm[p];
        const float m = eqm[(size_t)e * F + j];
        const int d = dst[e];
        const float* dn = disp_node + (size_t)d * 3 * F + j;
        a0 = fmaf(m, dn[0],     a0);
        a1 = fmaf(m, dn[F],     a1);
        a2 = fmaf(m, dn[2 * F], a2);
    }
    const size_t b = (size_t)n * 3 * F + j;
    out_disp[b]         = disp_node[b] + a0;
    out_disp[b + F]     = disp_node[b + F] + a1;
    out_disp[b + 2 * F] = disp_node[b + 2 * F] + a2;
}

// out_disp[n,d,j] += sum_{e in CSR[n]} eq3i[dst[e],j]*agg1[dst[e],d,j]
__global__ __launch_bounds__(128) void gather_eq3_kernel(
    const float* __restrict__ eq3i, const float* __restrict__ agg1,
    const int* __restrict__ dst, const int* __restrict__ offsets,
    const int* __restrict__ perm, float* __restrict__ out_disp, int N)
{
    const int n = blockIdx.x;
    if (n >= N) return;
    const int j = threadIdx.x;
    const int p1 = offsets[n + 1];
    float a0 = 0.0f, a1 = 0.0f, a2 = 0.0f;
    for (int p = offsets[n]; p < p1; ++p) {
        const int e = perm[p];
        const int d = dst[e];
        const float g = eq3i[(size_t)d * F + j];
        const float* a = agg1 + (size_t)d * 3 * F + j;
        a0 = fmaf(g, a[0],     a0);
        a1 = fmaf(g, a[F],     a1);
        a2 = fmaf(g, a[2 * F], a2);
    }
    const size_t b = (size_t)n * 3 * F + j;
    out_disp[b]         += a0;
    out_disp[b + F]     += a1;
    out_disp[b + 2 * F] += a2;
}

// Final per-node: u = mlp2(atom_new, upd) * sum_d(-force_out*disp_out);
// out_atom = LayerNorm(atom_new + u). One node per 128-thread block.
__global__ __launch_bounds__(128) void update_ln_kernel(
    const float* __restrict__ atom_new,
    const float* __restrict__ W1, const float* __restrict__ b1,
    const float* __restrict__ W2, const float* __restrict__ b2,
    const float* __restrict__ out_force, const float* __restrict__ out_disp,
    const float* __restrict__ ln_g, const float* __restrict__ ln_b,
    float* __restrict__ out_atom, int N)
{
    const int n = blockIdx.x;
    if (n >= N) return;
    const int j = threadIdx.x;
    __shared__ __align__(16) float hid[F];
    __shared__ float red[4];

    const float* x = atom_new + (size_t)n * F;
    const float4* x4 = (const float4*)x;
    float a1 = b1[j];
#pragma unroll 4
    for (int k4 = 0; k4 < 32; ++k4) {
        const float4 xv = x4[k4];
        const int k = 4 * k4;
        a1 = fmaf(xv.x, W1[(k + 0) * F + j], a1);
        a1 = fmaf(xv.y, W1[(k + 1) * F + j], a1);
        a1 = fmaf(xv.z, W1[(k + 2) * F + j], a1);
        a1 = fmaf(xv.w, W1[(k + 3) * F + j], a1);
    }
    hid[j] = silu_f(a1);
    __syncthreads();

    float a2 = b2[j];
    const float4* h4 = (const float4*)hid;
#pragma unroll 4
    for (int k4 = 0; k4 < 32; ++k4) {
        const float4 hv = h4[k4];
        const int k = 4 * k4;
        a2 = fmaf(hv.x, W2[(k + 0) * F + j], a2);
        a2 = fmaf(hv.y, W2[(k + 1) * F + j], a2);
        a2 = fmaf(hv.z, W2[(k + 2) * F + j], a2);
        a2 = fmaf(hv.w, W2[(k + 3) * F + j], a2);
    }

    const float* fo = out_force + (size_t)n * (3 * F) + j;
    const float* dl = out_disp + (size_t)n * (3 * F) + j;
    const float s = -(fo[0] * dl[0] + fo[F] * dl[F] + fo[2 * F] * dl[2 * F]);
    const float y = x[j] + a2 * s;

    float sy = y, syy = y * y;
#pragma unroll
    for (int m = 1; m < 64; m <<= 1) {
        sy  += __shfl_xor(sy, m);
        syy += __shfl_xor(syy, m);
    }
    if ((j & 63) == 0) {
        red[(j >> 6) * 2 + 0] = sy;
        red[(j >> 6) * 2 + 1] = syy;
    }
    __syncthreads();
    const float tsy  = red[0] + red[2];
    const float tsyy = red[1] + red[3];
    const float mu = tsy * (1.0f / F);
    float var = tsyy * (1.0f / F) - mu * mu;
    if (var < 0.0f) var = 0.0f;
    const float rstd = rsqrtf(var + 1e-5f);
    out_atom[(size_t)n * F + j] = (y - mu) * rstd * ln_g[j] + ln_b[j];
}

extern "C" void kernel_launch(void* const* d_in, const int* in_sizes, int n_in,
                              void* d_out, int out_size, void* d_ws, size_t ws_size,
                              hipStream_t stream)
{
    const float* atom_node  = (const float*)d_in[0];
    const float* force_node = (const float*)d_in[1];
    const float* disp_node  = (const float*)d_in[2];
    const float* disp_edge  = (const float*)d_in[3];
    const float* dist_edge  = (const float*)d_in[4];
    const int*   edge_index = (const int*)d_in[5];
    const float* nmp_W1 = (const float*)d_in[6];
    const float* nmp_b1 = (const float*)d_in[7];
    const float* nmp_W2 = (const float*)d_in[8];
    const float* nmp_b2 = (const float*)d_in[9];
    const float* emp_W  = (const float*)d_in[10];
    const float* emp_b  = (const float*)d_in[11];
    const float* eq1_W1 = (const float*)d_in[12];
    const float* eq1_b1 = (const float*)d_in[13];
    const float* eq1_W2 = (const float*)d_in[14];
    const float* eq1_b2 = (const float*)d_in[15];
    const float* eq2_W1 = (const float*)d_in[16];
    const float* eq2_b1 = (const float*)d_in[17];
    const float* eq2_W2 = (const float*)d_in[18];
    const float* eq2_b2 = (const float*)d_in[19];
    const float* eq3_W1 = (const float*)d_in[20];
    const float* eq3_W2 = (const float*)d_in[21];
    const float* upd_W1 = (const float*)d_in[22];
    const float* upd_b1 = (const float*)d_in[23];
    const float* upd_W2 = (const float*)d_in[24];
    const float* upd_b2 = (const float*)d_in[25];
    const float* ln_g   = (const float*)d_in[26];
    const float* ln_b   = (const float*)d_in[27];

    const int N = in_sizes[0] / F;       // 10000
    const int E = in_sizes[4] / NB;      // 200000
    const int* src = edge_index;
    const int* dst = edge_index + E;
    const int nF = N * F, n3F = N * 3 * F;

    float* out_atom  = (float*)d_out;
    float* out_force = out_atom + (size_t)nF;
    float* out_disp  = out_force + (size_t)n3F;

    // ---- workspace layout ----
    // ints first: counts[N], offsets[N+1], cursor[N], perm[E]  (pad to x4)
    int* counts  = (int*)d_ws;
    int* offsets = counts + N;
    int* cursor  = offsets + (N + 1);
    int* perm    = cursor + N;
    size_t int_slots = ((size_t)(3 * N + 1 + E) + 3) & ~(size_t)3;

    float* fbase    = (float*)d_ws + int_slots;
    float* h        = fbase;                       // N*F
    float* atom_new = h + (size_t)nF;              // N*F
    float* eq3i     = atom_new + (size_t)nF;       // N*F
    float* agg1     = eq3i + (size_t)nF;           // N*3*F
    float* inv_msg  = agg1 + (size_t)n3F;          // E*F
    float* eqm      = inv_msg + (size_t)E * F;     // E*F (reused for eq1 then eq2)
    float* hid      = eqm + (size_t)E * F;         // CH*F (chunked hidden buffer)

    const size_t fixed = int_slots + (size_t)6 * nF + (size_t)2 * E * F;
    long long avail = (long long)(ws_size / sizeof(float)) - (long long)fixed;
    long long ch_rows = (avail > 0 ? avail : 0) / F;
    ch_rows &= ~15LL;
    if (ch_rows < N) ch_rows = N;   // node-level passes need N rows of hid
    if (ch_rows > E) ch_rows = E;
    const int CH = (int)ch_rows;

    // ---- CSR build ----
    zero_counts_kernel<<<64, 256, 0, stream>>>(counts, N);
    csr_count_kernel<<<256, 256, 0, stream>>>(src, counts, E);
    csr_scan_kernel<<<1, 1024, 0, stream>>>(counts, offsets, cursor, N);
    csr_perm_kernel<<<256, 256, 0, stream>>>(src, cursor, perm, E);

    // ---- h = mlp2(atom_node, nmp) ----
    gemm128_kernel<true,  true><<<(N + 15) / 16, 128, 0, stream>>>(atom_node, nmp_W1, nmp_b1, hid, N);
    gemm128_kernel<false, true><<<(N + 15) / 16, 128, 0, stream>>>(hid, nmp_W2, nmp_b2, h, N);

    // ---- invariant message + node aggregation ----
    edge_inv_kernel<<<(E + 1) / 2, 256, 0, stream>>>(dist_edge, emp_W, emp_b, h,
                                                     src, dst, inv_msg, E);
    gather_inv_kernel<<<N, 128, 0, stream>>>(inv_msg, offsets, perm, atom_node,
                                             atom_new, N);

    // ---- eq1: eqm = mlp2(inv_msg, eq1); gather * disp_edge -> agg1, out_force ----
    for (int c0 = 0; c0 < E; c0 += CH) {
        const int c = (E - c0 < CH) ? (E - c0) : CH;
        gemm128_kernel<true,  true><<<(c + 15) / 16, 128, 0, stream>>>(
            inv_msg + (size_t)c0 * F, eq1_W1, eq1_b1, hid, c);
        gemm128_kernel<false, true><<<(c + 15) / 16, 128, 0, stream>>>(
            hid, eq1_W2, eq1_b2, eqm + (size_t)c0 * F, c);
    }
    gather_eq1_kernel<<<N, 128, 0, stream>>>(eqm, disp_edge, offsets, perm,
                                             force_node, agg1, out_force, N);

    // ---- eq2: eqm = mlp2(inv_msg, eq2); gather * disp_node[dst] -> out_disp ----
    for (int c0 = 0; c0 < E; c0 += CH) {
        const int c = (E - c0 < CH) ? (E - c0) : CH;
        gemm128_kernel<true,  true><<<(c + 15) / 16, 128, 0, stream>>>(
            inv_msg + (size_t)c0 * F, eq2_W1, eq2_b1, hid, c);
        gemm128_kernel<false, true><<<(c + 15) / 16, 128, 0, stream>>>(
            hid, eq2_W2, eq2_b2, eqm + (size_t)c0 * F, c);
    }
    gather_eq2_kernel<<<N, 128, 0, stream>>>(eqm, disp_node, dst, offsets, perm,
                                             out_disp, N);

    // ---- eq3: eq3i = mlp2_nobias(atom_new); gather * agg1[dst] -> out_disp ----
    gemm128_kernel<true,  false><<<(N + 15) / 16, 128, 0, stream>>>(atom_new, eq3_W1, nullptr, hid, N);
    gemm128_kernel<false, false><<<(N + 15) / 16, 128, 0, stream>>>(hid, eq3_W2, nullptr, eq3i, N);
    gather_eq3_kernel<<<N, 128, 0, stream>>>(eq3i, agg1, dst, offsets, perm,
                                             out_disp, N);

    // ---- final invariant update + layernorm ----
    update_ln_kernel<<<N, 128, 0, stream>>>(atom_new, upd_W1, upd_b1, upd_W2, upd_b2,
                                            out_force, out_disp, ln_g, ln_b, out_atom, N);
}

// Round 3
// 878.699 us; speedup vs baseline: 2.6608x; 2.6608x over previous
//
#include <hip/hip_runtime.h>
#include <hip/hip_bf16.h>

#define F 128
#define NB 20

typedef __attribute__((ext_vector_type(8))) short short8;
typedef __attribute__((ext_vector_type(4))) float floatx4;

__device__ __forceinline__ float silu_f(float x) {
    return x * (1.0f / (1.0f + __expf(-x)));
}

// ---------------- fp32 node-level GEMM (10k rows; kept from R1) ----------------

template<int R>
__device__ __forceinline__ void gemm_acc(
    const float* __restrict__ X, const float* __restrict__ W,
    int r0, int rows, int j, float* acc)
{
    const float4* __restrict__ X4 = (const float4*)X;
    int rbase[R];
#pragma unroll
    for (int r = 0; r < R; ++r) {
        int rr = r0 + r;
        rbase[r] = (rr < rows ? rr : rows - 1) * 32;
    }
#pragma unroll 2
    for (int k4 = 0; k4 < 32; ++k4) {
        const int k = k4 * 4;
        const float w0 = W[(k + 0) * F + j];
        const float w1 = W[(k + 1) * F + j];
        const float w2 = W[(k + 2) * F + j];
        const float w3 = W[(k + 3) * F + j];
#pragma unroll
        for (int r = 0; r < R; ++r) {
            const float4 xv = X4[rbase[r] + k4];
            acc[r] = fmaf(xv.x, w0, acc[r]);
            acc[r] = fmaf(xv.y, w1, acc[r]);
            acc[r] = fmaf(xv.z, w2, acc[r]);
            acc[r] = fmaf(xv.w, w3, acc[r]);
        }
    }
}

template<bool SILU, bool BIAS>
__global__ __launch_bounds__(128) void gemm128_kernel(
    const float* __restrict__ X, const float* __restrict__ W,
    const float* __restrict__ b, float* __restrict__ Y, int rows)
{
    constexpr int R = 16;
    const int j = threadIdx.x;
    const int r0 = blockIdx.x * R;
    float acc[R];
    const float bj = BIAS ? b[j] : 0.0f;
#pragma unroll
    for (int r = 0; r < R; ++r) acc[r] = bj;
    gemm_acc<R>(X, W, r0, rows, j, acc);
#pragma unroll
    for (int r = 0; r < R; ++r) {
        const int row = r0 + r;
        if (row < rows) {
            float v = acc[r];
            if (SILU) v = silu_f(v);
            Y[(size_t)row * F + j] = v;
        }
    }
}

// ---------------- bf16 MFMA GEMM for the 200k-row edge MLPs ----------------
// Y[M,128] = maybe_silu(X[M,128] @ W + b), X bf16, W given transposed n-major
// (Wt[n][k] bf16), Y bf16. Block = 256 thr = 4 waves; BM=128 rows/block;
// wave w -> rows [w*32, w*32+32), all 128 cols = 2x8 tiles of 16x16, K=128
// in 4 MFMA steps. Fragments loaded directly from global (A has zero reuse
// within a block -> LDS staging would be a pure round-trip; Wt is 32 KB,
// L1-resident). Layouts per guide §3 (m89/m91/m120 verified):
//   A: lane holds A[m=lane&15][k=quad*8+j]   (16B contiguous -> short8)
//   B: lane holds B[k=quad*8+j][n=lane&15]   -> contiguous in Wt[n][k]
//   C/D: col=lane&15, row=quad*4+reg
template<bool SILU>
__global__ __launch_bounds__(256) void mfma_gemm_kernel(
    const __hip_bfloat16* __restrict__ X,
    const __hip_bfloat16* __restrict__ Wt,
    const float* __restrict__ bias,
    __hip_bfloat16* __restrict__ Y, int Mp)
{
    const int t = threadIdx.x;
    const int wave = t >> 6;
    const int lane = t & 63;
    const int quad = lane >> 4;
    const int l16  = lane & 15;
    const int row0 = blockIdx.x * 128 + wave * 32;

    floatx4 acc[2][8];
#pragma unroll
    for (int rt = 0; rt < 2; ++rt)
#pragma unroll
        for (int ct = 0; ct < 8; ++ct)
            acc[rt][ct] = (floatx4){0.f, 0.f, 0.f, 0.f};

#pragma unroll
    for (int ks = 0; ks < 4; ++ks) {
        const int k0 = ks * 32 + quad * 8;
        short8 a[2], b[8];
#pragma unroll
        for (int rt = 0; rt < 2; ++rt)
            a[rt] = *(const short8*)(X + (size_t)(row0 + rt * 16 + l16) * F + k0);
#pragma unroll
        for (int ct = 0; ct < 8; ++ct)
            b[ct] = *(const short8*)(Wt + (size_t)(ct * 16 + l16) * F + k0);
#pragma unroll
        for (int rt = 0; rt < 2; ++rt)
#pragma unroll
            for (int ct = 0; ct < 8; ++ct)
                acc[rt][ct] = __builtin_amdgcn_mfma_f32_16x16x32_bf16(
                    a[rt], b[ct], acc[rt][ct], 0, 0, 0);
    }

#pragma unroll
    for (int rt = 0; rt < 2; ++rt) {
#pragma unroll
        for (int ct = 0; ct < 8; ++ct) {
            const int col = ct * 16 + l16;
            const float bj = bias[col];
#pragma unroll
            for (int r = 0; r < 4; ++r) {
                const int row = row0 + rt * 16 + quad * 4 + r;
                float v = acc[rt][ct][r] + bj;
                if (SILU) v = silu_f(v);
                Y[(size_t)row * F + col] = __float2bfloat16(v);
            }
        }
    }
}

// Convert 4 weight matrices [k][n] fp32 -> transposed bf16 Wt[n][k].
__global__ void prep_weights_kernel(
    const float* __restrict__ W0, const float* __restrict__ W1,
    const float* __restrict__ W2, const float* __restrict__ W3,
    __hip_bfloat16* __restrict__ Wt)
{
    const int t = blockIdx.x * 256 + threadIdx.x;
    if (t >= 4 * F * F) return;
    const int w = t >> 14;            // which matrix
    const int idx = t & (F * F - 1);  // n*128 + k
    const int n = idx >> 7;
    const int k = idx & 127;
    const float* W = (w == 0) ? W0 : (w == 1) ? W1 : (w == 2) ? W2 : W3;
    Wt[t] = __float2bfloat16(W[k * F + n]);
}

// ---------------- CSR build (edges grouped by src) ----------------

__global__ void zero_counts_kernel(int* __restrict__ counts, int N) {
    const int stride = gridDim.x * blockDim.x;
    for (int i = blockIdx.x * blockDim.x + threadIdx.x; i < N; i += stride)
        counts[i] = 0;
}

__global__ void csr_count_kernel(const int* __restrict__ src,
                                 int* __restrict__ counts, int E) {
    const int stride = gridDim.x * blockDim.x;
    for (int e = blockIdx.x * blockDim.x + threadIdx.x; e < E; e += stride)
        atomicAdd(&counts[src[e]], 1);
}

__global__ __launch_bounds__(1024) void csr_scan_kernel(
    const int* __restrict__ counts, int* __restrict__ offsets,
    int* __restrict__ cursor, int N)
{
    constexpr int T = 1024;
    const int t = threadIdx.x;
    const int per = (N + T - 1) / T;
    const int base = t * per;
    int lsum = 0;
    for (int i = 0; i < per; ++i) {
        int idx = base + i;
        if (idx < N) lsum += counts[idx];
    }
    __shared__ int s[T];
    s[t] = lsum;
    __syncthreads();
    for (int off = 1; off < T; off <<= 1) {
        int v = (t >= off) ? s[t - off] : 0;
        __syncthreads();
        s[t] += v;
        __syncthreads();
    }
    int run = s[t] - lsum;
    for (int i = 0; i < per; ++i) {
        int idx = base + i;
        if (idx < N) {
            offsets[idx] = run;
            cursor[idx] = run;
            run += counts[idx];
        }
    }
    if (t == T - 1) offsets[N] = run;
}

__global__ void csr_perm_kernel(const int* __restrict__ src,
                                int* __restrict__ cursor,
                                int* __restrict__ perm, int E) {
    const int stride = gridDim.x * blockDim.x;
    for (int e = blockIdx.x * blockDim.x + threadIdx.x; e < E; e += stride) {
        int pos = atomicAdd(&cursor[src[e]], 1);
        perm[pos] = e;
    }
}

// ---------------- edge kernels ----------------

// inv_msg[e] = (dist_edge[e]@emp_W + emp_b) * h[src] * h[dst], bf16 out;
// rows E..Mp zero-padded (feeds MFMA GEMM tiles).
__global__ __launch_bounds__(256) void edge_inv_kernel(
    const float* __restrict__ dist_edge, const float* __restrict__ emp_W,
    const float* __restrict__ emp_b, const float* __restrict__ h,
    const int* __restrict__ src, const int* __restrict__ dst,
    __hip_bfloat16* __restrict__ inv_msg, int E, int Mp)
{
    const int t = blockIdx.x * 256 + threadIdx.x;
    const int e = t >> 7;
    const int j = t & 127;
    if (e >= Mp) return;
    if (e >= E) { inv_msg[(size_t)e * F + j] = __float2bfloat16(0.0f); return; }
    float acc = emp_b[j];
#pragma unroll
    for (int k = 0; k < NB; ++k)
        acc = fmaf(dist_edge[(size_t)e * NB + k], emp_W[k * F + j], acc);
    const int s = src[e];
    const int d = dst[e];
    const float m = acc * h[(size_t)s * F + j] * h[(size_t)d * F + j];
    inv_msg[(size_t)e * F + j] = __float2bfloat16(m);
}

// ---------------- per-node register gathers (no atomics) ----------------

__global__ __launch_bounds__(128) void gather_inv_kernel(
    const __hip_bfloat16* __restrict__ inv_msg, const int* __restrict__ offsets,
    const int* __restrict__ perm, const float* __restrict__ atom,
    float* __restrict__ atom_new, int N)
{
    const int n = blockIdx.x;
    if (n >= N) return;
    const int j = threadIdx.x;
    const int p1 = offsets[n + 1];
    float acc = 0.0f;
    for (int p = offsets[n]; p < p1; ++p) {
        const int e = perm[p];
        acc += __bfloat162float(inv_msg[(size_t)e * F + j]);
    }
    atom_new[(size_t)n * F + j] = atom[(size_t)n * F + j] + acc;
}

__global__ __launch_bounds__(128) void gather_eq1_kernel(
    const __hip_bfloat16* __restrict__ eqm, const float* __restrict__ disp_edge,
    const int* __restrict__ offsets, const int* __restrict__ perm,
    const float* __restrict__ force, float* __restrict__ agg1,
    float* __restrict__ out_force, int N)
{
    const int n = blockIdx.x;
    if (n >= N) return;
    const int j = threadIdx.x;
    const int p1 = offsets[n + 1];
    float a0 = 0.0f, a1 = 0.0f, a2 = 0.0f;
    for (int p = offsets[n]; p < p1; ++p) {
        const int e = perm[p];
        const float m = __bfloat162float(eqm[(size_t)e * F + j]);
        a0 = fmaf(m, disp_edge[(size_t)e * 3 + 0], a0);
        a1 = fmaf(m, disp_edge[(size_t)e * 3 + 1], a1);
        a2 = fmaf(m, disp_edge[(size_t)e * 3 + 2], a2);
    }
    const size_t b = (size_t)n * 3 * F + j;
    agg1[b]         = a0;
    agg1[b + F]     = a1;
    agg1[b + 2 * F] = a2;
    out_force[b]         = force[b] + a0;
    out_force[b + F]     = force[b + F] + a1;
    out_force[b + 2 * F] = force[b + 2 * F] + a2;
}

__global__ __launch_bounds__(128) void gather_eq2_kernel(
    const __hip_bfloat16* __restrict__ eqm, const float* __restrict__ disp_node,
    const int* __restrict__ dst, const int* __restrict__ offsets,
    const int* __restrict__ perm, float* __restrict__ out_disp, int N)
{
    const int n = blockIdx.x;
    if (n >= N) return;
    const int j = threadIdx.x;
    const int p1 = offsets[n + 1];
    float a0 = 0.0f, a1 = 0.0f, a2 = 0.0f;
    for (int p = offsets[n]; p < p1; ++p) {
        const int e = perm[p];
        const float m = __bfloat162float(eqm[(size_t)e * F + j]);
        const int d = dst[e];
        const float* dn = disp_node + (size_t)d * 3 * F + j;
        a0 = fmaf(m, dn[0],     a0);
        a1 = fmaf(m, dn[F],     a1);
        a2 = fmaf(m, dn[2 * F], a2);
    }
    const size_t b = (size_t)n * 3 * F + j;
    out_disp[b]         = disp_node[b] + a0;
    out_disp[b + F]     = disp_node[b + F] + a1;
    out_disp[b + 2 * F] = disp_node[b + 2 * F] + a2;
}

__global__ __launch_bounds__(128) void gather_eq3_kernel(
    const float* __restrict__ eq3i, const float* __restrict__ agg1,
    const int* __restrict__ dst, const int* __restrict__ offsets,
    const int* __restrict__ perm, float* __restrict__ out_disp, int N)
{
    const int n = blockIdx.x;
    if (n >= N) return;
    const int j = threadIdx.x;
    const int p1 = offsets[n + 1];
    float a0 = 0.0f, a1 = 0.0f, a2 = 0.0f;
    for (int p = offsets[n]; p < p1; ++p) {
        const int e = perm[p];
        const int d = dst[e];
        const float g = eq3i[(size_t)d * F + j];
        const float* a = agg1 + (size_t)d * 3 * F + j;
        a0 = fmaf(g, a[0],     a0);
        a1 = fmaf(g, a[F],     a1);
        a2 = fmaf(g, a[2 * F], a2);
    }
    const size_t b = (size_t)n * 3 * F + j;
    out_disp[b]         += a0;
    out_disp[b + F]     += a1;
    out_disp[b + 2 * F] += a2;
}

// ---------------- final update + LN ----------------

__global__ __launch_bounds__(128) void update_ln_kernel(
    const float* __restrict__ atom_new,
    const float* __restrict__ W1, const float* __restrict__ b1,
    const float* __restrict__ W2, const float* __restrict__ b2,
    const float* __restrict__ out_force, const float* __restrict__ out_disp,
    const float* __restrict__ ln_g, const float* __restrict__ ln_b,
    float* __restrict__ out_atom, int N)
{
    const int n = blockIdx.x;
    if (n >= N) return;
    const int j = threadIdx.x;
    __shared__ __align__(16) float hid[F];
    __shared__ float red[4];

    const float* x = atom_new + (size_t)n * F;
    const float4* x4 = (const float4*)x;
    float a1 = b1[j];
#pragma unroll 4
    for (int k4 = 0; k4 < 32; ++k4) {
        const float4 xv = x4[k4];
        const int k = 4 * k4;
        a1 = fmaf(xv.x, W1[(k + 0) * F + j], a1);
        a1 = fmaf(xv.y, W1[(k + 1) * F + j], a1);
        a1 = fmaf(xv.z, W1[(k + 2) * F + j], a1);
        a1 = fmaf(xv.w, W1[(k + 3) * F + j], a1);
    }
    hid[j] = silu_f(a1);
    __syncthreads();

    float a2 = b2[j];
    const float4* h4 = (const float4*)hid;
#pragma unroll 4
    for (int k4 = 0; k4 < 32; ++k4) {
        const float4 hv = h4[k4];
        const int k = 4 * k4;
        a2 = fmaf(hv.x, W2[(k + 0) * F + j], a2);
        a2 = fmaf(hv.y, W2[(k + 1) * F + j], a2);
        a2 = fmaf(hv.z, W2[(k + 2) * F + j], a2);
        a2 = fmaf(hv.w, W2[(k + 3) * F + j], a2);
    }

    const float* fo = out_force + (size_t)n * (3 * F) + j;
    const float* dl = out_disp + (size_t)n * (3 * F) + j;
    const float s = -(fo[0] * dl[0] + fo[F] * dl[F] + fo[2 * F] * dl[2 * F]);
    const float y = x[j] + a2 * s;

    float sy = y, syy = y * y;
#pragma unroll
    for (int m = 1; m < 64; m <<= 1) {
        sy  += __shfl_xor(sy, m);
        syy += __shfl_xor(syy, m);
    }
    if ((j & 63) == 0) {
        red[(j >> 6) * 2 + 0] = sy;
        red[(j >> 6) * 2 + 1] = syy;
    }
    __syncthreads();
    const float tsy  = red[0] + red[2];
    const float tsyy = red[1] + red[3];
    const float mu = tsy * (1.0f / F);
    float var = tsyy * (1.0f / F) - mu * mu;
    if (var < 0.0f) var = 0.0f;
    const float rstd = rsqrtf(var + 1e-5f);
    out_atom[(size_t)n * F + j] = (y - mu) * rstd * ln_g[j] + ln_b[j];
}

extern "C" void kernel_launch(void* const* d_in, const int* in_sizes, int n_in,
                              void* d_out, int out_size, void* d_ws, size_t ws_size,
                              hipStream_t stream)
{
    const float* atom_node  = (const float*)d_in[0];
    const float* force_node = (const float*)d_in[1];
    const float* disp_node  = (const float*)d_in[2];
    const float* disp_edge  = (const float*)d_in[3];
    const float* dist_edge  = (const float*)d_in[4];
    const int*   edge_index = (const int*)d_in[5];
    const float* nmp_W1 = (const float*)d_in[6];
    const float* nmp_b1 = (const float*)d_in[7];
    const float* nmp_W2 = (const float*)d_in[8];
    const float* nmp_b2 = (const float*)d_in[9];
    const float* emp_W  = (const float*)d_in[10];
    const float* emp_b  = (const float*)d_in[11];
    const float* eq1_W1 = (const float*)d_in[12];
    const float* eq1_b1 = (const float*)d_in[13];
    const float* eq1_W2 = (const float*)d_in[14];
    const float* eq1_b2 = (const float*)d_in[15];
    const float* eq2_W1 = (const float*)d_in[16];
    const float* eq2_b1 = (const float*)d_in[17];
    const float* eq2_W2 = (const float*)d_in[18];
    const float* eq2_b2 = (const float*)d_in[19];
    const float* eq3_W1 = (const float*)d_in[20];
    const float* eq3_W2 = (const float*)d_in[21];
    const float* upd_W1 = (const float*)d_in[22];
    const float* upd_b1 = (const float*)d_in[23];
    const float* upd_W2 = (const float*)d_in[24];
    const float* upd_b2 = (const float*)d_in[25];
    const float* ln_g   = (const float*)d_in[26];
    const float* ln_b   = (const float*)d_in[27];

    const int N = in_sizes[0] / F;       // 10000
    const int E = in_sizes[4] / NB;      // 200000
    const int Mp = ((E + 127) / 128) * 128;  // 200064 (pad to MFMA tile)
    const int* src = edge_index;
    const int* dst = edge_index + E;
    const int nF = N * F, n3F = N * 3 * F;

    float* out_atom  = (float*)d_out;
    float* out_force = out_atom + (size_t)nF;
    float* out_disp  = out_force + (size_t)n3F;

    // ---- workspace layout (bytes, aligned) ----
    char* p = (char*)d_ws;
    int* counts  = (int*)p;
    int* offsets = counts + N;
    int* cursor  = offsets + (N + 1);
    int* perm    = cursor + N;
    size_t off = (size_t)(3 * N + 1 + E) * sizeof(int);
    off = (off + 63) & ~(size_t)63;

    float* h        = (float*)(p + off); off += (size_t)nF * 4;
    float* atom_new = (float*)(p + off); off += (size_t)nF * 4;
    float* eq3i     = (float*)(p + off); off += (size_t)nF * 4;
    float* hidN     = (float*)(p + off); off += (size_t)nF * 4;
    float* agg1     = (float*)(p + off); off += (size_t)n3F * 4;
    off = (off + 63) & ~(size_t)63;

    __hip_bfloat16* Xbf = (__hip_bfloat16*)(p + off); off += (size_t)Mp * F * 2;
    __hip_bfloat16* Hbf = (__hip_bfloat16*)(p + off); off += (size_t)Mp * F * 2;
    __hip_bfloat16* Qbf = (__hip_bfloat16*)(p + off); off += (size_t)Mp * F * 2;
    __hip_bfloat16* Wt  = (__hip_bfloat16*)(p + off); // 4 * F * F bf16
    __hip_bfloat16* Wt_eq1a = Wt;
    __hip_bfloat16* Wt_eq1b = Wt + 1 * F * F;
    __hip_bfloat16* Wt_eq2a = Wt + 2 * F * F;
    __hip_bfloat16* Wt_eq2b = Wt + 3 * F * F;

    // ---- weight prep + CSR build ----
    prep_weights_kernel<<<(4 * F * F) / 256, 256, 0, stream>>>(
        eq1_W1, eq1_W2, eq2_W1, eq2_W2, Wt);
    zero_counts_kernel<<<64, 256, 0, stream>>>(counts, N);
    csr_count_kernel<<<256, 256, 0, stream>>>(src, counts, E);
    csr_scan_kernel<<<1, 1024, 0, stream>>>(counts, offsets, cursor, N);
    csr_perm_kernel<<<256, 256, 0, stream>>>(src, cursor, perm, E);

    // ---- h = mlp2(atom_node, nmp)  (fp32, node-level) ----
    gemm128_kernel<true,  true><<<(N + 15) / 16, 128, 0, stream>>>(atom_node, nmp_W1, nmp_b1, hidN, N);
    gemm128_kernel<false, true><<<(N + 15) / 16, 128, 0, stream>>>(hidN, nmp_W2, nmp_b2, h, N);

    // ---- invariant message (bf16) + node aggregation ----
    edge_inv_kernel<<<Mp / 2, 256, 0, stream>>>(dist_edge, emp_W, emp_b, h,
                                                src, dst, Xbf, E, Mp);
    gather_inv_kernel<<<N, 128, 0, stream>>>(Xbf, offsets, perm, atom_node,
                                             atom_new, N);

    // ---- eq1 MLP (MFMA) + gather ----
    mfma_gemm_kernel<true ><<<Mp / 128, 256, 0, stream>>>(Xbf, Wt_eq1a, eq1_b1, Hbf, Mp);
    mfma_gemm_kernel<false><<<Mp / 128, 256, 0, stream>>>(Hbf, Wt_eq1b, eq1_b2, Qbf, Mp);
    gather_eq1_kernel<<<N, 128, 0, stream>>>(Qbf, disp_edge, offsets, perm,
                                             force_node, agg1, out_force, N);

    // ---- eq2 MLP (MFMA) + gather ----
    mfma_gemm_kernel<true ><<<Mp / 128, 256, 0, stream>>>(Xbf, Wt_eq2a, eq2_b1, Hbf, Mp);
    mfma_gemm_kernel<false><<<Mp / 128, 256, 0, stream>>>(Hbf, Wt_eq2b, eq2_b2, Qbf, Mp);
    gather_eq2_kernel<<<N, 128, 0, stream>>>(Qbf, disp_node, dst, offsets, perm,
                                             out_disp, N);

    // ---- eq3: node-level MLP (fp32) + gather ----
    gemm128_kernel<true,  false><<<(N + 15) / 16, 128, 0, stream>>>(atom_new, eq3_W1, nullptr, hidN, N);
    gemm128_kernel<false, false><<<(N + 15) / 16, 128, 0, stream>>>(hidN, eq3_W2, nullptr, eq3i, N);
    gather_eq3_kernel<<<N, 128, 0, stream>>>(eq3i, agg1, dst, offsets, perm,
                                             out_disp, N);

    // ---- final invariant update + layernorm ----
    update_ln_kernel<<<N, 128, 0, stream>>>(atom_new, upd_W1, upd_b1, upd_W2, upd_b2,
                                            out_force, out_disp, ln_g, ln_b, out_atom, N);
}

// Round 4
// 787.091 us; speedup vs baseline: 2.9704x; 1.1164x over previous
//
#include <hip/hip_runtime.h>
#include <hip/hip_bf16.h>

#define F 128
#define NB 20

typedef __attribute__((ext_vector_type(8))) short short8;
typedef __attribute__((ext_vector_type(4))) float floatx4;

__device__ __forceinline__ float silu_f(float x) {
    return x * (1.0f / (1.0f + __expf(-x)));
}

// ---------------- fp32 node-level GEMM (10k rows) ----------------

template<int R>
__device__ __forceinline__ void gemm_acc(
    const float* __restrict__ X, const float* __restrict__ W,
    int r0, int rows, int j, float* acc)
{
    const float4* __restrict__ X4 = (const float4*)X;
    int rbase[R];
#pragma unroll
    for (int r = 0; r < R; ++r) {
        int rr = r0 + r;
        rbase[r] = (rr < rows ? rr : rows - 1) * 32;
    }
#pragma unroll 2
    for (int k4 = 0; k4 < 32; ++k4) {
        const int k = k4 * 4;
        const float w0 = W[(k + 0) * F + j];
        const float w1 = W[(k + 1) * F + j];
        const float w2 = W[(k + 2) * F + j];
        const float w3 = W[(k + 3) * F + j];
#pragma unroll
        for (int r = 0; r < R; ++r) {
            const float4 xv = X4[rbase[r] + k4];
            acc[r] = fmaf(xv.x, w0, acc[r]);
            acc[r] = fmaf(xv.y, w1, acc[r]);
            acc[r] = fmaf(xv.z, w2, acc[r]);
            acc[r] = fmaf(xv.w, w3, acc[r]);
        }
    }
}

template<bool SILU, bool BIAS>
__global__ __launch_bounds__(128) void gemm128_kernel(
    const float* __restrict__ X, const float* __restrict__ W,
    const float* __restrict__ b, float* __restrict__ Y, int rows)
{
    constexpr int R = 16;
    const int j = threadIdx.x;
    const int r0 = blockIdx.x * R;
    float acc[R];
    const float bj = BIAS ? b[j] : 0.0f;
#pragma unroll
    for (int r = 0; r < R; ++r) acc[r] = bj;
    gemm_acc<R>(X, W, r0, rows, j, acc);
#pragma unroll
    for (int r = 0; r < R; ++r) {
        const int row = r0 + r;
        if (row < rows) {
            float v = acc[r];
            if (SILU) v = silu_f(v);
            Y[(size_t)row * F + j] = v;
        }
    }
}

// ---------------- fused 2-layer bf16 MFMA MLP for the 200k-row edge MLPs ----
// Y = (silu(X@W1+b1))@W2 + b2, all [*,128]x[128,128]. Block=256thr=4 waves,
// 128 rows/block. Layer1 accumulators -> silu -> LDS hid (row stride 136 bf16:
// keeps ds_read_b128 16B-aligned, 2-way bank aliasing only = free) -> reload
// as A-fragments -> layer2 MFMA. Saves the 51MB hidden write+read per pair.
// Fragment layouts per guide §3 (m89/m91 verified):
//   A: lane holds A[m=lane&15][k=quad*8+j] (16B contiguous)
//   B: lane holds B[k=quad*8+j][n=lane&15] -> contiguous in Wt[n][k]
//   C/D: col=lane&15, row=quad*4+reg
#define HSTRIDE 136

__global__ __launch_bounds__(256) void fused_mlp_kernel(
    const __hip_bfloat16* __restrict__ X,
    const __hip_bfloat16* __restrict__ Wt1, const float* __restrict__ b1,
    const __hip_bfloat16* __restrict__ Wt2, const float* __restrict__ b2,
    __hip_bfloat16* __restrict__ Y, int Mp)
{
    __shared__ __hip_bfloat16 hid[128 * HSTRIDE];
    const int t = threadIdx.x;
    const int wave = t >> 6;
    const int lane = t & 63;
    const int quad = lane >> 4;
    const int l16  = lane & 15;
    const int rloc0 = wave * 32;                 // block-local row base of this wave
    const int row0 = blockIdx.x * 128 + rloc0;   // global row base

    floatx4 acc[2][8];
#pragma unroll
    for (int rt = 0; rt < 2; ++rt)
#pragma unroll
        for (int ct = 0; ct < 8; ++ct)
            acc[rt][ct] = (floatx4){0.f, 0.f, 0.f, 0.f};

    // ---- layer 1: A from global ----
#pragma unroll
    for (int ks = 0; ks < 4; ++ks) {
        const int k0 = ks * 32 + quad * 8;
        short8 a[2], b[8];
#pragma unroll
        for (int rt = 0; rt < 2; ++rt)
            a[rt] = *(const short8*)(X + (size_t)(row0 + rt * 16 + l16) * F + k0);
#pragma unroll
        for (int ct = 0; ct < 8; ++ct)
            b[ct] = *(const short8*)(Wt1 + (size_t)(ct * 16 + l16) * F + k0);
#pragma unroll
        for (int rt = 0; rt < 2; ++rt)
#pragma unroll
            for (int ct = 0; ct < 8; ++ct)
                acc[rt][ct] = __builtin_amdgcn_mfma_f32_16x16x32_bf16(
                    a[rt], b[ct], acc[rt][ct], 0, 0, 0);
    }

    // ---- silu -> LDS ----
#pragma unroll
    for (int rt = 0; rt < 2; ++rt) {
#pragma unroll
        for (int ct = 0; ct < 8; ++ct) {
            const int col = ct * 16 + l16;
            const float bj = b1[col];
#pragma unroll
            for (int r = 0; r < 4; ++r) {
                const int rl = rloc0 + rt * 16 + quad * 4 + r;
                hid[rl * HSTRIDE + col] = __float2bfloat16(silu_f(acc[rt][ct][r] + bj));
            }
        }
    }
    __syncthreads();

    // ---- layer 2: A from LDS ----
#pragma unroll
    for (int rt = 0; rt < 2; ++rt)
#pragma unroll
        for (int ct = 0; ct < 8; ++ct)
            acc[rt][ct] = (floatx4){0.f, 0.f, 0.f, 0.f};

#pragma unroll
    for (int ks = 0; ks < 4; ++ks) {
        const int k0 = ks * 32 + quad * 8;
        short8 a[2], b[8];
#pragma unroll
        for (int rt = 0; rt < 2; ++rt)
            a[rt] = *(const short8*)(hid + (size_t)(rloc0 + rt * 16 + l16) * HSTRIDE + k0);
#pragma unroll
        for (int ct = 0; ct < 8; ++ct)
            b[ct] = *(const short8*)(Wt2 + (size_t)(ct * 16 + l16) * F + k0);
#pragma unroll
        for (int rt = 0; rt < 2; ++rt)
#pragma unroll
            for (int ct = 0; ct < 8; ++ct)
                acc[rt][ct] = __builtin_amdgcn_mfma_f32_16x16x32_bf16(
                    a[rt], b[ct], acc[rt][ct], 0, 0, 0);
    }

#pragma unroll
    for (int rt = 0; rt < 2; ++rt) {
#pragma unroll
        for (int ct = 0; ct < 8; ++ct) {
            const int col = ct * 16 + l16;
            const float bj = b2[col];
#pragma unroll
            for (int r = 0; r < 4; ++r) {
                const int row = row0 + rt * 16 + quad * 4 + r;
                Y[(size_t)row * F + col] = __float2bfloat16(acc[rt][ct][r] + bj);
            }
        }
    }
}

// Convert 4 weight matrices [k][n] fp32 -> transposed bf16 Wt[n][k].
__global__ void prep_weights_kernel(
    const float* __restrict__ W0, const float* __restrict__ W1,
    const float* __restrict__ W2, const float* __restrict__ W3,
    __hip_bfloat16* __restrict__ Wt)
{
    const int t = blockIdx.x * 256 + threadIdx.x;
    if (t >= 4 * F * F) return;
    const int w = t >> 14;
    const int idx = t & (F * F - 1);
    const int n = idx >> 7;
    const int k = idx & 127;
    const float* W = (w == 0) ? W0 : (w == 1) ? W1 : (w == 2) ? W2 : W3;
    Wt[t] = __float2bfloat16(W[k * F + n]);
}

// ---------------- CSR build (edges grouped by src) ----------------

__global__ void zero_counts_kernel(int* __restrict__ counts, int N) {
    const int stride = gridDim.x * blockDim.x;
    for (int i = blockIdx.x * blockDim.x + threadIdx.x; i < N; i += stride)
        counts[i] = 0;
}

__global__ void csr_count_kernel(const int* __restrict__ src,
                                 int* __restrict__ counts, int E) {
    const int stride = gridDim.x * blockDim.x;
    for (int e = blockIdx.x * blockDim.x + threadIdx.x; e < E; e += stride)
        atomicAdd(&counts[src[e]], 1);
}

__global__ __launch_bounds__(1024) void csr_scan_kernel(
    const int* __restrict__ counts, int* __restrict__ offsets,
    int* __restrict__ cursor, int N)
{
    constexpr int T = 1024;
    const int t = threadIdx.x;
    const int per = (N + T - 1) / T;
    const int base = t * per;
    int lsum = 0;
    for (int i = 0; i < per; ++i) {
        int idx = base + i;
        if (idx < N) lsum += counts[idx];
    }
    __shared__ int s[T];
    s[t] = lsum;
    __syncthreads();
    for (int off = 1; off < T; off <<= 1) {
        int v = (t >= off) ? s[t - off] : 0;
        __syncthreads();
        s[t] += v;
        __syncthreads();
    }
    int run = s[t] - lsum;
    for (int i = 0; i < per; ++i) {
        int idx = base + i;
        if (idx < N) {
            offsets[idx] = run;
            cursor[idx] = run;
            run += counts[idx];
        }
    }
    if (t == T - 1) offsets[N] = run;
}

__global__ void csr_perm_kernel(const int* __restrict__ src,
                                int* __restrict__ cursor,
                                int* __restrict__ perm, int E) {
    const int stride = gridDim.x * blockDim.x;
    for (int e = blockIdx.x * blockDim.x + threadIdx.x; e < E; e += stride) {
        int pos = atomicAdd(&cursor[src[e]], 1);
        perm[pos] = e;
    }
}

// ---------------- edge invariant message (register-blocked) ----------------
// inv_msg[e,j] = (dist_edge[e]@emp_W + emp_b)[j] * h[src[e],j] * h[dst[e],j]
// R=16 edges per 128-thread block: dist_edge rows via lane-uniform float4
// (scalar loads, SMEM pipe); emp_W read once per block; h gathers batched.
__global__ __launch_bounds__(128) void edge_inv_kernel(
    const float* __restrict__ dist_edge, const float* __restrict__ emp_W,
    const float* __restrict__ emp_b, const float* __restrict__ h,
    const int* __restrict__ src, const int* __restrict__ dst,
    __hip_bfloat16* __restrict__ inv_msg, int E, int Mp)
{
    constexpr int R = 16;
    const int j = threadIdx.x;
    const int e0 = blockIdx.x * R;

    // batched gathers first (overlap with MLP compute)
    float hs[R], hd[R];
#pragma unroll
    for (int r = 0; r < R; ++r) {
        const int e = e0 + r;
        const int s = (e < E) ? src[e] : 0;
        const int d = (e < E) ? dst[e] : 0;
        hs[r] = h[(size_t)s * F + j];
        hd[r] = h[(size_t)d * F + j];
    }

    float acc[R];
    const float bj = emp_b[j];
#pragma unroll
    for (int r = 0; r < R; ++r) acc[r] = bj;

    const float4* de4 = (const float4*)dist_edge;  // rows are 80B -> 16B aligned
#pragma unroll
    for (int k4 = 0; k4 < NB / 4; ++k4) {
        const float w0 = emp_W[(k4 * 4 + 0) * F + j];
        const float w1 = emp_W[(k4 * 4 + 1) * F + j];
        const float w2 = emp_W[(k4 * 4 + 2) * F + j];
        const float w3 = emp_W[(k4 * 4 + 3) * F + j];
#pragma unroll
        for (int r = 0; r < R; ++r) {
            const int e = e0 + r;
            const float4 dv = de4[(size_t)((e < E) ? e : 0) * (NB / 4) + k4];
            acc[r] = fmaf(dv.x, w0, acc[r]);
            acc[r] = fmaf(dv.y, w1, acc[r]);
            acc[r] = fmaf(dv.z, w2, acc[r]);
            acc[r] = fmaf(dv.w, w3, acc[r]);
        }
    }

#pragma unroll
    for (int r = 0; r < R; ++r) {
        const int e = e0 + r;
        if (e < Mp) {
            const float m = (e < E) ? acc[r] * hs[r] * hd[r] : 0.0f;
            inv_msg[(size_t)e * F + j] = __float2bfloat16(m);
        }
    }
}

// ---------------- per-node register gathers (no atomics) ----------------

__global__ __launch_bounds__(128) void gather_inv_kernel(
    const __hip_bfloat16* __restrict__ inv_msg, const int* __restrict__ offsets,
    const int* __restrict__ perm, const float* __restrict__ atom,
    float* __restrict__ atom_new, int N)
{
    const int n = blockIdx.x;
    if (n >= N) return;
    const int j = threadIdx.x;
    const int p1 = offsets[n + 1];
    float acc = 0.0f;
    for (int p = offsets[n]; p < p1; ++p) {
        const int e = perm[p];
        acc += __bfloat162float(inv_msg[(size_t)e * F + j]);
    }
    atom_new[(size_t)n * F + j] = atom[(size_t)n * F + j] + acc;
}

__global__ __launch_bounds__(128) void gather_eq1_kernel(
    const __hip_bfloat16* __restrict__ eqm, const float* __restrict__ disp_edge,
    const int* __restrict__ offsets, const int* __restrict__ perm,
    const float* __restrict__ force, float* __restrict__ agg1,
    float* __restrict__ out_force, int N)
{
    const int n = blockIdx.x;
    if (n >= N) return;
    const int j = threadIdx.x;
    const int p1 = offsets[n + 1];
    float a0 = 0.0f, a1 = 0.0f, a2 = 0.0f;
    for (int p = offsets[n]; p < p1; ++p) {
        const int e = perm[p];
        const float m = __bfloat162float(eqm[(size_t)e * F + j]);
        a0 = fmaf(m, disp_edge[(size_t)e * 3 + 0], a0);
        a1 = fmaf(m, disp_edge[(size_t)e * 3 + 1], a1);
        a2 = fmaf(m, disp_edge[(size_t)e * 3 + 2], a2);
    }
    const size_t b = (size_t)n * 3 * F + j;
    agg1[b]         = a0;
    agg1[b + F]     = a1;
    agg1[b + 2 * F] = a2;
    out_force[b]         = force[b] + a0;
    out_force[b + F]     = force[b + F] + a1;
    out_force[b + 2 * F] = force[b + 2 * F] + a2;
}

__global__ __launch_bounds__(128) void gather_eq2_kernel(
    const __hip_bfloat16* __restrict__ eqm, const float* __restrict__ disp_node,
    const int* __restrict__ dst, const int* __restrict__ offsets,
    const int* __restrict__ perm, float* __restrict__ out_disp, int N)
{
    const int n = blockIdx.x;
    if (n >= N) return;
    const int j = threadIdx.x;
    const int p1 = offsets[n + 1];
    float a0 = 0.0f, a1 = 0.0f, a2 = 0.0f;
    for (int p = offsets[n]; p < p1; ++p) {
        const int e = perm[p];
        const float m = __bfloat162float(eqm[(size_t)e * F + j]);
        const int d = dst[e];
        const float* dn = disp_node + (size_t)d * 3 * F + j;
        a0 = fmaf(m, dn[0],     a0);
        a1 = fmaf(m, dn[F],     a1);
        a2 = fmaf(m, dn[2 * F], a2);
    }
    const size_t b = (size_t)n * 3 * F + j;
    out_disp[b]         = disp_node[b] + a0;
    out_disp[b + F]     = disp_node[b + F] + a1;
    out_disp[b + 2 * F] = disp_node[b + 2 * F] + a2;
}

__global__ __launch_bounds__(128) void gather_eq3_kernel(
    const float* __restrict__ eq3i, const float* __restrict__ agg1,
    const int* __restrict__ dst, const int* __restrict__ offsets,
    const int* __restrict__ perm, float* __restrict__ out_disp, int N)
{
    const int n = blockIdx.x;
    if (n >= N) return;
    const int j = threadIdx.x;
    const int p1 = offsets[n + 1];
    float a0 = 0.0f, a1 = 0.0f, a2 = 0.0f;
    for (int p = offsets[n]; p < p1; ++p) {
        const int e = perm[p];
        const int d = dst[e];
        const float g = eq3i[(size_t)d * F + j];
        const float* a = agg1 + (size_t)d * 3 * F + j;
        a0 = fmaf(g, a[0],     a0);
        a1 = fmaf(g, a[F],     a1);
        a2 = fmaf(g, a[2 * F], a2);
    }
    const size_t b = (size_t)n * 3 * F + j;
    out_disp[b]         += a0;
    out_disp[b + F]     += a1;
    out_disp[b + 2 * F] += a2;
}

// ---------------- final update + LN ----------------

__global__ __launch_bounds__(128) void update_ln_kernel(
    const float* __restrict__ atom_new,
    const float* __restrict__ W1, const float* __restrict__ b1,
    const float* __restrict__ W2, const float* __restrict__ b2,
    const float* __restrict__ out_force, const float* __restrict__ out_disp,
    const float* __restrict__ ln_g, const float* __restrict__ ln_b,
    float* __restrict__ out_atom, int N)
{
    const int n = blockIdx.x;
    if (n >= N) return;
    const int j = threadIdx.x;
    __shared__ __align__(16) float hid[F];
    __shared__ float red[4];

    const float* x = atom_new + (size_t)n * F;
    const float4* x4 = (const float4*)x;
    float a1 = b1[j];
#pragma unroll 4
    for (int k4 = 0; k4 < 32; ++k4) {
        const float4 xv = x4[k4];
        const int k = 4 * k4;
        a1 = fmaf(xv.x, W1[(k + 0) * F + j], a1);
        a1 = fmaf(xv.y, W1[(k + 1) * F + j], a1);
        a1 = fmaf(xv.z, W1[(k + 2) * F + j], a1);
        a1 = fmaf(xv.w, W1[(k + 3) * F + j], a1);
    }
    hid[j] = silu_f(a1);
    __syncthreads();

    float a2 = b2[j];
    const float4* h4 = (const float4*)hid;
#pragma unroll 4
    for (int k4 = 0; k4 < 32; ++k4) {
        const float4 hv = h4[k4];
        const int k = 4 * k4;
        a2 = fmaf(hv.x, W2[(k + 0) * F + j], a2);
        a2 = fmaf(hv.y, W2[(k + 1) * F + j], a2);
        a2 = fmaf(hv.z, W2[(k + 2) * F + j], a2);
        a2 = fmaf(hv.w, W2[(k + 3) * F + j], a2);
    }

    const float* fo = out_force + (size_t)n * (3 * F) + j;
    const float* dl = out_disp + (size_t)n * (3 * F) + j;
    const float s = -(fo[0] * dl[0] + fo[F] * dl[F] + fo[2 * F] * dl[2 * F]);
    const float y = x[j] + a2 * s;

    float sy = y, syy = y * y;
#pragma unroll
    for (int m = 1; m < 64; m <<= 1) {
        sy  += __shfl_xor(sy, m);
        syy += __shfl_xor(syy, m);
    }
    if ((j & 63) == 0) {
        red[(j >> 6) * 2 + 0] = sy;
        red[(j >> 6) * 2 + 1] = syy;
    }
    __syncthreads();
    const float tsy  = red[0] + red[2];
    const float tsyy = red[1] + red[3];
    const float mu = tsy * (1.0f / F);
    float var = tsyy * (1.0f / F) - mu * mu;
    if (var < 0.0f) var = 0.0f;
    const float rstd = rsqrtf(var + 1e-5f);
    out_atom[(size_t)n * F + j] = (y - mu) * rstd * ln_g[j] + ln_b[j];
}

extern "C" void kernel_launch(void* const* d_in, const int* in_sizes, int n_in,
                              void* d_out, int out_size, void* d_ws, size_t ws_size,
                              hipStream_t stream)
{
    const float* atom_node  = (const float*)d_in[0];
    const float* force_node = (const float*)d_in[1];
    const float* disp_node  = (const float*)d_in[2];
    const float* disp_edge  = (const float*)d_in[3];
    const float* dist_edge  = (const float*)d_in[4];
    const int*   edge_index = (const int*)d_in[5];
    const float* nmp_W1 = (const float*)d_in[6];
    const float* nmp_b1 = (const float*)d_in[7];
    const float* nmp_W2 = (const float*)d_in[8];
    const float* nmp_b2 = (const float*)d_in[9];
    const float* emp_W  = (const float*)d_in[10];
    const float* emp_b  = (const float*)d_in[11];
    const float* eq1_W1 = (const float*)d_in[12];
    const float* eq1_b1 = (const float*)d_in[13];
    const float* eq1_W2 = (const float*)d_in[14];
    const float* eq1_b2 = (const float*)d_in[15];
    const float* eq2_W1 = (const float*)d_in[16];
    const float* eq2_b1 = (const float*)d_in[17];
    const float* eq2_W2 = (const float*)d_in[18];
    const float* eq2_b2 = (const float*)d_in[19];
    const float* eq3_W1 = (const float*)d_in[20];
    const float* eq3_W2 = (const float*)d_in[21];
    const float* upd_W1 = (const float*)d_in[22];
    const float* upd_b1 = (const float*)d_in[23];
    const float* upd_W2 = (const float*)d_in[24];
    const float* upd_b2 = (const float*)d_in[25];
    const float* ln_g   = (const float*)d_in[26];
    const float* ln_b   = (const float*)d_in[27];

    const int N = in_sizes[0] / F;           // 10000
    const int E = in_sizes[4] / NB;          // 200000
    const int Mp = ((E + 127) / 128) * 128;  // 200064
    const int* src = edge_index;
    const int* dst = edge_index + E;
    const int nF = N * F, n3F = N * 3 * F;

    float* out_atom  = (float*)d_out;
    float* out_force = out_atom + (size_t)nF;
    float* out_disp  = out_force + (size_t)n3F;

    // ---- workspace layout ----
    char* p = (char*)d_ws;
    int* counts  = (int*)p;
    int* offsets = counts + N;
    int* cursor  = offsets + (N + 1);
    int* perm    = cursor + N;
    size_t off = (size_t)(3 * N + 1 + E) * sizeof(int);
    off = (off + 63) & ~(size_t)63;

    float* h        = (float*)(p + off); off += (size_t)nF * 4;
    float* atom_new = (float*)(p + off); off += (size_t)nF * 4;
    float* eq3i     = (float*)(p + off); off += (size_t)nF * 4;
    float* hidN     = (float*)(p + off); off += (size_t)nF * 4;
    float* agg1     = (float*)(p + off); off += (size_t)n3F * 4;
    off = (off + 63) & ~(size_t)63;

    __hip_bfloat16* Xbf = (__hip_bfloat16*)(p + off); off += (size_t)Mp * F * 2;
    __hip_bfloat16* Qbf = (__hip_bfloat16*)(p + off); off += (size_t)Mp * F * 2;
    __hip_bfloat16* Wt  = (__hip_bfloat16*)(p + off); // 4 * F * F bf16
    __hip_bfloat16* Wt_eq1a = Wt;
    __hip_bfloat16* Wt_eq1b = Wt + 1 * F * F;
    __hip_bfloat16* Wt_eq2a = Wt + 2 * F * F;
    __hip_bfloat16* Wt_eq2b = Wt + 3 * F * F;

    // ---- weight prep + CSR build ----
    prep_weights_kernel<<<(4 * F * F) / 256, 256, 0, stream>>>(
        eq1_W1, eq1_W2, eq2_W1, eq2_W2, Wt);
    zero_counts_kernel<<<64, 256, 0, stream>>>(counts, N);
    csr_count_kernel<<<256, 256, 0, stream>>>(src, counts, E);
    csr_scan_kernel<<<1, 1024, 0, stream>>>(counts, offsets, cursor, N);
    csr_perm_kernel<<<256, 256, 0, stream>>>(src, cursor, perm, E);

    // ---- h = mlp2(atom_node, nmp)  (fp32, node-level) ----
    gemm128_kernel<true,  true><<<(N + 15) / 16, 128, 0, stream>>>(atom_node, nmp_W1, nmp_b1, hidN, N);
    gemm128_kernel<false, true><<<(N + 15) / 16, 128, 0, stream>>>(hidN, nmp_W2, nmp_b2, h, N);

    // ---- invariant message (bf16, register-blocked) + node aggregation ----
    edge_inv_kernel<<<Mp / 16, 128, 0, stream>>>(dist_edge, emp_W, emp_b, h,
                                                 src, dst, Xbf, E, Mp);
    gather_inv_kernel<<<N, 128, 0, stream>>>(Xbf, offsets, perm, atom_node,
                                             atom_new, N);

    // ---- eq1 MLP (fused 2-layer MFMA) + gather ----
    fused_mlp_kernel<<<Mp / 128, 256, 0, stream>>>(Xbf, Wt_eq1a, eq1_b1,
                                                   Wt_eq1b, eq1_b2, Qbf, Mp);
    gather_eq1_kernel<<<N, 128, 0, stream>>>(Qbf, disp_edge, offsets, perm,
                                             force_node, agg1, out_force, N);

    // ---- eq2 MLP (fused 2-layer MFMA) + gather ----
    fused_mlp_kernel<<<Mp / 128, 256, 0, stream>>>(Xbf, Wt_eq2a, eq2_b1,
                                                   Wt_eq2b, eq2_b2, Qbf, Mp);
    gather_eq2_kernel<<<N, 128, 0, stream>>>(Qbf, disp_node, dst, offsets, perm,
                                             out_disp, N);

    // ---- eq3: node-level MLP (fp32) + gather ----
    gemm128_kernel<true,  false><<<(N + 15) / 16, 128, 0, stream>>>(atom_new, eq3_W1, nullptr, hidN, N);
    gemm128_kernel<false, false><<<(N + 15) / 16, 128, 0, stream>>>(hidN, eq3_W2, nullptr, eq3i, N);
    gather_eq3_kernel<<<N, 128, 0, stream>>>(eq3i, agg1, dst, offsets, perm,
                                             out_disp, N);

    // ---- final invariant update + layernorm ----
    update_ln_kernel<<<N, 128, 0, stream>>>(atom_new, upd_W1, upd_b1, upd_W2, upd_b2,
                                            out_force, out_disp, ln_g, ln_b, out_atom, N);
}

// Round 5
// 635.524 us; speedup vs baseline: 3.6789x; 1.2385x over previous
//
#include <hip/hip_runtime.h>
#include <hip/hip_bf16.h>

#define F 128
#define NB 20
#define HSTRIDE 136

typedef __attribute__((ext_vector_type(8))) short short8;
typedef __attribute__((ext_vector_type(4))) short short4v;
typedef __attribute__((ext_vector_type(4))) float floatx4;

__device__ __forceinline__ float silu_f(float x) {
    // fast: x * rcp(1 + e^-x); v_rcp_f32 approx is plenty for bf16-rounded outputs
    return x * __builtin_amdgcn_rcpf(1.0f + __expf(-x));
}

// ---------------- fused 2-layer bf16 MFMA MLP ----------------
// Y = (silu(X@W1+b1))@W2 + b2, [Mp,128]x[128,128]x[128,128].
// Operand roles swapped vs naive: A = weight tile (Wt[n][k]), B = X tile.
// Then D[row=feature][col=edge]: each lane holds 4 CONTIGUOUS features of one
// edge -> 8-B packed bf16 stores / ds_write_b64, and layer-2 LDS reads are
// 16-B ds_read_b128. Global fragment loads are identical to the unswapped
// version (A/B layouts are mutual transposes). Block=256=4 waves, 128 rows.
template<typename OUT_T, bool BIAS>
__global__ __launch_bounds__(256) void fused_mlp_kernel(
    const __hip_bfloat16* __restrict__ X,
    const __hip_bfloat16* __restrict__ Wt1, const float* __restrict__ b1,
    const __hip_bfloat16* __restrict__ Wt2, const float* __restrict__ b2,
    OUT_T* __restrict__ Y, int Mp)
{
    __shared__ __hip_bfloat16 hid[128 * HSTRIDE];
    const int t = threadIdx.x;
    const int wave = t >> 6;
    const int lane = t & 63;
    const int quad = lane >> 4;
    const int l16  = lane & 15;
    const int eloc0 = wave * 32;                 // block-local edge base
    const int e0 = blockIdx.x * 128 + eloc0;     // global edge base

    floatx4 acc[8][2];   // [feature tile][edge tile]
#pragma unroll
    for (int ft = 0; ft < 8; ++ft)
#pragma unroll
        for (int et = 0; et < 2; ++et)
            acc[ft][et] = (floatx4){0.f, 0.f, 0.f, 0.f};

    // ---- layer 1 ----
#pragma unroll
    for (int ks = 0; ks < 4; ++ks) {
        const int k0 = ks * 32 + quad * 8;
        short8 bx[2], aw[8];
#pragma unroll
        for (int et = 0; et < 2; ++et)
            bx[et] = *(const short8*)(X + (size_t)(e0 + et * 16 + l16) * F + k0);
#pragma unroll
        for (int ft = 0; ft < 8; ++ft)
            aw[ft] = *(const short8*)(Wt1 + (size_t)(ft * 16 + l16) * F + k0);
#pragma unroll
        for (int ft = 0; ft < 8; ++ft)
#pragma unroll
            for (int et = 0; et < 2; ++et)
                acc[ft][et] = __builtin_amdgcn_mfma_f32_16x16x32_bf16(
                    aw[ft], bx[et], acc[ft][et], 0, 0, 0);
    }

    // ---- silu -> LDS (8-B packed) ----
#pragma unroll
    for (int ft = 0; ft < 8; ++ft) {
        const int feat = ft * 16 + quad * 4;
        floatx4 bv = (floatx4){0.f, 0.f, 0.f, 0.f};
        if (BIAS) bv = *(const floatx4*)(b1 + feat);
#pragma unroll
        for (int et = 0; et < 2; ++et) {
            const int el = eloc0 + et * 16 + l16;
            __align__(8) __hip_bfloat16 tmp[4];
#pragma unroll
            for (int r = 0; r < 4; ++r)
                tmp[r] = __float2bfloat16(silu_f(acc[ft][et][r] + bv[r]));
            *(short4v*)(hid + (size_t)el * HSTRIDE + feat) = *(const short4v*)tmp;
        }
    }
    __syncthreads();

    // ---- layer 2 ----
#pragma unroll
    for (int ft = 0; ft < 8; ++ft)
#pragma unroll
        for (int et = 0; et < 2; ++et)
            acc[ft][et] = (floatx4){0.f, 0.f, 0.f, 0.f};

#pragma unroll
    for (int ks = 0; ks < 4; ++ks) {
        const int k0 = ks * 32 + quad * 8;
        short8 bx[2], aw[8];
#pragma unroll
        for (int et = 0; et < 2; ++et)
            bx[et] = *(const short8*)(hid + (size_t)(eloc0 + et * 16 + l16) * HSTRIDE + k0);
#pragma unroll
        for (int ft = 0; ft < 8; ++ft)
            aw[ft] = *(const short8*)(Wt2 + (size_t)(ft * 16 + l16) * F + k0);
#pragma unroll
        for (int ft = 0; ft < 8; ++ft)
#pragma unroll
            for (int et = 0; et < 2; ++et)
                acc[ft][et] = __builtin_amdgcn_mfma_f32_16x16x32_bf16(
                    aw[ft], bx[et], acc[ft][et], 0, 0, 0);
    }

    // ---- epilogue: packed stores ----
#pragma unroll
    for (int ft = 0; ft < 8; ++ft) {
        const int feat = ft * 16 + quad * 4;
        floatx4 bv = (floatx4){0.f, 0.f, 0.f, 0.f};
        if (BIAS) bv = *(const floatx4*)(b2 + feat);
#pragma unroll
        for (int et = 0; et < 2; ++et) {
            const int e = e0 + et * 16 + l16;
            if (sizeof(OUT_T) == 2) {
                __align__(8) __hip_bfloat16 tmp[4];
#pragma unroll
                for (int r = 0; r < 4; ++r)
                    tmp[r] = __float2bfloat16(acc[ft][et][r] + bv[r]);
                *(short4v*)((__hip_bfloat16*)Y + (size_t)e * F + feat) = *(const short4v*)tmp;
            } else {
                floatx4 v;
#pragma unroll
                for (int r = 0; r < 4; ++r) v[r] = acc[ft][et][r] + bv[r];
                *(floatx4*)((float*)Y + (size_t)e * F + feat) = v;
            }
        }
    }
}

// Convert 8 weight matrices [k][n] fp32 -> transposed bf16 Wt[n][k].
__global__ void prep_weights_kernel(
    const float* __restrict__ W0, const float* __restrict__ W1,
    const float* __restrict__ W2, const float* __restrict__ W3,
    const float* __restrict__ W4, const float* __restrict__ W5,
    const float* __restrict__ W6, const float* __restrict__ W7,
    __hip_bfloat16* __restrict__ Wt)
{
    const int t = blockIdx.x * 256 + threadIdx.x;
    if (t >= 8 * F * F) return;
    const int w = t >> 14;
    const int idx = t & (F * F - 1);
    const int n = idx >> 7;
    const int k = idx & 127;
    const float* W = (w == 0) ? W0 : (w == 1) ? W1 : (w == 2) ? W2 : (w == 3) ? W3
                   : (w == 4) ? W4 : (w == 5) ? W5 : (w == 6) ? W6 : W7;
    Wt[t] = __float2bfloat16(W[k * F + n]);
}

__global__ void cast_pad_kernel(const float* __restrict__ src,
                                __hip_bfloat16* __restrict__ dst,
                                int n_valid, int n_total)
{
    const int stride = gridDim.x * blockDim.x;
    for (int i = blockIdx.x * blockDim.x + threadIdx.x; i < n_total; i += stride)
        dst[i] = __float2bfloat16(i < n_valid ? src[i] : 0.0f);
}

__global__ void pad_zero_bf_kernel(__hip_bfloat16* __restrict__ dst,
                                   int from, int to)
{
    const int i = from + blockIdx.x * 256 + threadIdx.x;
    if (i < to) dst[i] = __float2bfloat16(0.0f);
}

// ---------------- CSR build (edges grouped by src) ----------------

__global__ void zero_counts_kernel(int* __restrict__ counts, int N) {
    const int stride = gridDim.x * blockDim.x;
    for (int i = blockIdx.x * blockDim.x + threadIdx.x; i < N; i += stride)
        counts[i] = 0;
}

__global__ void csr_count_kernel(const int* __restrict__ src,
                                 int* __restrict__ counts, int E) {
    const int stride = gridDim.x * blockDim.x;
    for (int e = blockIdx.x * blockDim.x + threadIdx.x; e < E; e += stride)
        atomicAdd(&counts[src[e]], 1);
}

__global__ __launch_bounds__(1024) void csr_scan_kernel(
    const int* __restrict__ counts, int* __restrict__ offsets,
    int* __restrict__ cursor, int N)
{
    constexpr int T = 1024;
    const int t = threadIdx.x;
    const int per = (N + T - 1) / T;
    const int base = t * per;
    int lsum = 0;
    for (int i = 0; i < per; ++i) {
        int idx = base + i;
        if (idx < N) lsum += counts[idx];
    }
    __shared__ int s[T];
    s[t] = lsum;
    __syncthreads();
    for (int off = 1; off < T; off <<= 1) {
        int v = (t >= off) ? s[t - off] : 0;
        __syncthreads();
        s[t] += v;
        __syncthreads();
    }
    int run = s[t] - lsum;
    for (int i = 0; i < per; ++i) {
        int idx = base + i;
        if (idx < N) {
            offsets[idx] = run;
            cursor[idx] = run;
            run += counts[idx];
        }
    }
    if (t == T - 1) offsets[N] = run;
}

__global__ void csr_perm_kernel(const int* __restrict__ src,
                                int* __restrict__ cursor,
                                int* __restrict__ perm, int E) {
    const int stride = gridDim.x * blockDim.x;
    for (int e = blockIdx.x * blockDim.x + threadIdx.x; e < E; e += stride) {
        int pos = atomicAdd(&cursor[src[e]], 1);
        perm[pos] = e;
    }
}

// ---------------- edge invariant message (register-blocked) ----------------

__global__ __launch_bounds__(128) void edge_inv_kernel(
    const float* __restrict__ dist_edge, const float* __restrict__ emp_W,
    const float* __restrict__ emp_b, const __hip_bfloat16* __restrict__ h,
    const int* __restrict__ src, const int* __restrict__ dst,
    __hip_bfloat16* __restrict__ inv_msg, int E, int Mp)
{
    constexpr int R = 16;
    const int j = threadIdx.x;
    const int e0 = blockIdx.x * R;

    float hs[R], hd[R];
#pragma unroll
    for (int r = 0; r < R; ++r) {
        const int e = e0 + r;
        const int s = (e < E) ? src[e] : 0;
        const int d = (e < E) ? dst[e] : 0;
        hs[r] = __bfloat162float(h[(size_t)s * F + j]);
        hd[r] = __bfloat162float(h[(size_t)d * F + j]);
    }

    float acc[R];
    const float bj = emp_b[j];
#pragma unroll
    for (int r = 0; r < R; ++r) acc[r] = bj;

    const float4* de4 = (const float4*)dist_edge;
#pragma unroll
    for (int k4 = 0; k4 < NB / 4; ++k4) {
        const float w0 = emp_W[(k4 * 4 + 0) * F + j];
        const float w1 = emp_W[(k4 * 4 + 1) * F + j];
        const float w2 = emp_W[(k4 * 4 + 2) * F + j];
        const float w3 = emp_W[(k4 * 4 + 3) * F + j];
#pragma unroll
        for (int r = 0; r < R; ++r) {
            const int e = e0 + r;
            const float4 dv = de4[(size_t)((e < E) ? e : 0) * (NB / 4) + k4];
            acc[r] = fmaf(dv.x, w0, acc[r]);
            acc[r] = fmaf(dv.y, w1, acc[r]);
            acc[r] = fmaf(dv.z, w2, acc[r]);
            acc[r] = fmaf(dv.w, w3, acc[r]);
        }
    }

#pragma unroll
    for (int r = 0; r < R; ++r) {
        const int e = e0 + r;
        if (e < Mp) {
            const float m = (e < E) ? acc[r] * hs[r] * hd[r] : 0.0f;
            inv_msg[(size_t)e * F + j] = __float2bfloat16(m);
        }
    }
}

// ---------------- per-node register gathers (no atomics) ----------------

__global__ __launch_bounds__(128) void gather_inv_kernel(
    const __hip_bfloat16* __restrict__ inv_msg, const int* __restrict__ offsets,
    const int* __restrict__ perm, const float* __restrict__ atom,
    float* __restrict__ atom_new, __hip_bfloat16* __restrict__ atom_new_bf, int N)
{
    const int n = blockIdx.x;
    if (n >= N) return;
    const int j = threadIdx.x;
    const int p1 = offsets[n + 1];
    float acc = 0.0f;
    for (int p = offsets[n]; p < p1; ++p) {
        const int e = perm[p];
        acc += __bfloat162float(inv_msg[(size_t)e * F + j]);
    }
    const float v = atom[(size_t)n * F + j] + acc;
    atom_new[(size_t)n * F + j] = v;
    atom_new_bf[(size_t)n * F + j] = __float2bfloat16(v);
}

__global__ __launch_bounds__(128) void gather_eq1_kernel(
    const __hip_bfloat16* __restrict__ eqm, const float* __restrict__ disp_edge,
    const int* __restrict__ offsets, const int* __restrict__ perm,
    const float* __restrict__ force, float* __restrict__ agg1,
    float* __restrict__ out_force, int N)
{
    const int n = blockIdx.x;
    if (n >= N) return;
    const int j = threadIdx.x;
    const int p1 = offsets[n + 1];
    float a0 = 0.0f, a1 = 0.0f, a2 = 0.0f;
    for (int p = offsets[n]; p < p1; ++p) {
        const int e = perm[p];
        const float m = __bfloat162float(eqm[(size_t)e * F + j]);
        a0 = fmaf(m, disp_edge[(size_t)e * 3 + 0], a0);
        a1 = fmaf(m, disp_edge[(size_t)e * 3 + 1], a1);
        a2 = fmaf(m, disp_edge[(size_t)e * 3 + 2], a2);
    }
    const size_t b = (size_t)n * 3 * F + j;
    agg1[b]         = a0;
    agg1[b + F]     = a1;
    agg1[b + 2 * F] = a2;
    out_force[b]         = force[b] + a0;
    out_force[b + F]     = force[b + F] + a1;
    out_force[b + 2 * F] = force[b + 2 * F] + a2;
}

// merged eq2+eq3 gather:
// out_disp[n,d,j] = disp_node[n,d,j]
//   + sum_e eqm2[e,j]*disp_node[dst[e],d,j]        (eq2)
//   + sum_e eq3i[dst[e],j]*agg1[dst[e],d,j]        (eq3)
__global__ __launch_bounds__(128) void gather_eq23_kernel(
    const __hip_bfloat16* __restrict__ eqm2, const __hip_bfloat16* __restrict__ eq3i,
    const float* __restrict__ agg1, const float* __restrict__ disp_node,
    const int* __restrict__ dst, const int* __restrict__ offsets,
    const int* __restrict__ perm, float* __restrict__ out_disp, int N)
{
    const int n = blockIdx.x;
    if (n >= N) return;
    const int j = threadIdx.x;
    const int p1 = offsets[n + 1];
    float a0 = 0.0f, a1 = 0.0f, a2 = 0.0f;
    for (int p = offsets[n]; p < p1; ++p) {
        const int e = perm[p];
        const int d = dst[e];
        const float m = __bfloat162float(eqm2[(size_t)e * F + j]);
        const float g = __bfloat162float(eq3i[(size_t)d * F + j]);
        const float* dn = disp_node + (size_t)d * 3 * F + j;
        const float* ag = agg1 + (size_t)d * 3 * F + j;
        a0 += m * dn[0]     + g * ag[0];
        a1 += m * dn[F]     + g * ag[F];
        a2 += m * dn[2 * F] + g * ag[2 * F];
    }
    const size_t b = (size_t)n * 3 * F + j;
    out_disp[b]         = disp_node[b] + a0;
    out_disp[b + F]     = disp_node[b + F] + a1;
    out_disp[b + 2 * F] = disp_node[b + 2 * F] + a2;
}

// ---------------- final update + LN (fp32, per-node block) ----------------

__global__ __launch_bounds__(128) void update_ln_kernel(
    const float* __restrict__ atom_new,
    const float* __restrict__ W1, const float* __restrict__ b1,
    const float* __restrict__ W2, const float* __restrict__ b2,
    const float* __restrict__ out_force, const float* __restrict__ out_disp,
    const float* __restrict__ ln_g, const float* __restrict__ ln_b,
    float* __restrict__ out_atom, int N)
{
    const int n = blockIdx.x;
    if (n >= N) return;
    const int j = threadIdx.x;
    __shared__ __align__(16) float hid[F];
    __shared__ float red[4];

    const float* x = atom_new + (size_t)n * F;
    const float4* x4 = (const float4*)x;
    float a1 = b1[j];
#pragma unroll 4
    for (int k4 = 0; k4 < 32; ++k4) {
        const float4 xv = x4[k4];
        const int k = 4 * k4;
        a1 = fmaf(xv.x, W1[(k + 0) * F + j], a1);
        a1 = fmaf(xv.y, W1[(k + 1) * F + j], a1);
        a1 = fmaf(xv.z, W1[(k + 2) * F + j], a1);
        a1 = fmaf(xv.w, W1[(k + 3) * F + j], a1);
    }
    hid[j] = silu_f(a1);
    __syncthreads();

    float a2 = b2[j];
    const float4* h4 = (const float4*)hid;
#pragma unroll 4
    for (int k4 = 0; k4 < 32; ++k4) {
        const float4 hv = h4[k4];
        const int k = 4 * k4;
        a2 = fmaf(hv.x, W2[(k + 0) * F + j], a2);
        a2 = fmaf(hv.y, W2[(k + 1) * F + j], a2);
        a2 = fmaf(hv.z, W2[(k + 2) * F + j], a2);
        a2 = fmaf(hv.w, W2[(k + 3) * F + j], a2);
    }

    const float* fo = out_force + (size_t)n * (3 * F) + j;
    const float* dl = out_disp + (size_t)n * (3 * F) + j;
    const float s = -(fo[0] * dl[0] + fo[F] * dl[F] + fo[2 * F] * dl[2 * F]);
    const float y = x[j] + a2 * s;

    float sy = y, syy = y * y;
#pragma unroll
    for (int m = 1; m < 64; m <<= 1) {
        sy  += __shfl_xor(sy, m);
        syy += __shfl_xor(syy, m);
    }
    if ((j & 63) == 0) {
        red[(j >> 6) * 2 + 0] = sy;
        red[(j >> 6) * 2 + 1] = syy;
    }
    __syncthreads();
    const float tsy  = red[0] + red[2];
    const float tsyy = red[1] + red[3];
    const float mu = tsy * (1.0f / F);
    float var = tsyy * (1.0f / F) - mu * mu;
    if (var < 0.0f) var = 0.0f;
    const float rstd = rsqrtf(var + 1e-5f);
    out_atom[(size_t)n * F + j] = (y - mu) * rstd * ln_g[j] + ln_b[j];
}

extern "C" void kernel_launch(void* const* d_in, const int* in_sizes, int n_in,
                              void* d_out, int out_size, void* d_ws, size_t ws_size,
                              hipStream_t stream)
{
    const float* atom_node  = (const float*)d_in[0];
    const float* force_node = (const float*)d_in[1];
    const float* disp_node  = (const float*)d_in[2];
    const float* disp_edge  = (const float*)d_in[3];
    const float* dist_edge  = (const float*)d_in[4];
    const int*   edge_index = (const int*)d_in[5];
    const float* nmp_W1 = (const float*)d_in[6];
    const float* nmp_b1 = (const float*)d_in[7];
    const float* nmp_W2 = (const float*)d_in[8];
    const float* nmp_b2 = (const float*)d_in[9];
    const float* emp_W  = (const float*)d_in[10];
    const float* emp_b  = (const float*)d_in[11];
    const float* eq1_W1 = (const float*)d_in[12];
    const float* eq1_b1 = (const float*)d_in[13];
    const float* eq1_W2 = (const float*)d_in[14];
    const float* eq1_b2 = (const float*)d_in[15];
    const float* eq2_W1 = (const float*)d_in[16];
    const float* eq2_b1 = (const float*)d_in[17];
    const float* eq2_W2 = (const float*)d_in[18];
    const float* eq2_b2 = (const float*)d_in[19];
    const float* eq3_W1 = (const float*)d_in[20];
    const float* eq3_W2 = (const float*)d_in[21];
    const float* upd_W1 = (const float*)d_in[22];
    const float* upd_b1 = (const float*)d_in[23];
    const float* upd_W2 = (const float*)d_in[24];
    const float* upd_b2 = (const float*)d_in[25];
    const float* ln_g   = (const float*)d_in[26];
    const float* ln_b   = (const float*)d_in[27];

    const int N = in_sizes[0] / F;            // 10000
    const int E = in_sizes[4] / NB;           // 200000
    const int Mp  = ((E + 127) / 128) * 128;  // 200064
    const int Mp2 = ((N + 127) / 128) * 128;  // 10112
    const int* src = edge_index;
    const int* dst = edge_index + E;
    const int nF = N * F, n3F = N * 3 * F;

    float* out_atom  = (float*)d_out;
    float* out_force = out_atom + (size_t)nF;
    float* out_disp  = out_force + (size_t)n3F;

    // ---- workspace layout ----
    char* p = (char*)d_ws;
    int* counts  = (int*)p;
    int* offsets = counts + N;
    int* cursor  = offsets + (N + 1);
    int* perm    = cursor + N;
    size_t off = (size_t)(3 * N + 1 + E) * sizeof(int);
    off = (off + 63) & ~(size_t)63;

    __hip_bfloat16* h_bf        = (__hip_bfloat16*)(p + off); off += (size_t)Mp2 * F * 2;
    __hip_bfloat16* atom_bf     = (__hip_bfloat16*)(p + off); off += (size_t)Mp2 * F * 2;
    __hip_bfloat16* atom_new_bf = (__hip_bfloat16*)(p + off); off += (size_t)Mp2 * F * 2;
    __hip_bfloat16* eq3i_bf     = (__hip_bfloat16*)(p + off); off += (size_t)Mp2 * F * 2;
    off = (off + 63) & ~(size_t)63;
    float* atom_new = (float*)(p + off); off += (size_t)nF * 4;
    float* agg1     = (float*)(p + off); off += (size_t)n3F * 4;
    off = (off + 63) & ~(size_t)63;
    __hip_bfloat16* Xbf = (__hip_bfloat16*)(p + off); off += (size_t)Mp * F * 2;
    __hip_bfloat16* Qbf = (__hip_bfloat16*)(p + off); off += (size_t)Mp * F * 2;
    __hip_bfloat16* Wt  = (__hip_bfloat16*)(p + off); // 8*F*F bf16
    __hip_bfloat16* Wt_eq1a = Wt + 0 * F * F;
    __hip_bfloat16* Wt_eq1b = Wt + 1 * F * F;
    __hip_bfloat16* Wt_eq2a = Wt + 2 * F * F;
    __hip_bfloat16* Wt_eq2b = Wt + 3 * F * F;
    __hip_bfloat16* Wt_nmpa = Wt + 4 * F * F;
    __hip_bfloat16* Wt_nmpb = Wt + 5 * F * F;
    __hip_bfloat16* Wt_eq3a = Wt + 6 * F * F;
    __hip_bfloat16* Wt_eq3b = Wt + 7 * F * F;

    // ---- prep: weights, casts, pads, CSR ----
    prep_weights_kernel<<<(8 * F * F) / 256, 256, 0, stream>>>(
        eq1_W1, eq1_W2, eq2_W1, eq2_W2, nmp_W1, nmp_W2, eq3_W1, eq3_W2, Wt);
    cast_pad_kernel<<<512, 256, 0, stream>>>(atom_node, atom_bf, nF, Mp2 * F);
    pad_zero_bf_kernel<<<(Mp2 * F - nF + 255) / 256, 256, 0, stream>>>(
        atom_new_bf, nF, Mp2 * F);
    zero_counts_kernel<<<64, 256, 0, stream>>>(counts, N);
    csr_count_kernel<<<256, 256, 0, stream>>>(src, counts, E);
    csr_scan_kernel<<<1, 1024, 0, stream>>>(counts, offsets, cursor, N);
    csr_perm_kernel<<<256, 256, 0, stream>>>(src, cursor, perm, E);

    // ---- h = mlp2(atom_node, nmp)  (MFMA, bf16 out) ----
    fused_mlp_kernel<__hip_bfloat16, true><<<Mp2 / 128, 256, 0, stream>>>(
        atom_bf, Wt_nmpa, nmp_b1, Wt_nmpb, nmp_b2, h_bf, Mp2);

    // ---- invariant message + node aggregation ----
    edge_inv_kernel<<<Mp / 16, 128, 0, stream>>>(dist_edge, emp_W, emp_b, h_bf,
                                                 src, dst, Xbf, E, Mp);
    gather_inv_kernel<<<N, 128, 0, stream>>>(Xbf, offsets, perm, atom_node,
                                             atom_new, atom_new_bf, N);

    // ---- eq1 MLP + gather (agg1, out_force) ----
    fused_mlp_kernel<__hip_bfloat16, true><<<Mp / 128, 256, 0, stream>>>(
        Xbf, Wt_eq1a, eq1_b1, Wt_eq1b, eq1_b2, Qbf, Mp);
    gather_eq1_kernel<<<N, 128, 0, stream>>>(Qbf, disp_edge, offsets, perm,
                                             force_node, agg1, out_force, N);

    // ---- eq2 MLP; eq3 gate MLP; merged eq2+eq3 gather ----
    fused_mlp_kernel<__hip_bfloat16, true><<<Mp / 128, 256, 0, stream>>>(
        Xbf, Wt_eq2a, eq2_b1, Wt_eq2b, eq2_b2, Qbf, Mp);
    fused_mlp_kernel<__hip_bfloat16, false><<<Mp2 / 128, 256, 0, stream>>>(
        atom_new_bf, Wt_eq3a, nullptr, Wt_eq3b, nullptr, eq3i_bf, Mp2);
    gather_eq23_kernel<<<N, 128, 0, stream>>>(Qbf, eq3i_bf, agg1, disp_node,
                                              dst, offsets, perm, out_disp, N);

    // ---- final invariant update + layernorm ----
    update_ln_kernel<<<N, 128, 0, stream>>>(atom_new, upd_W1, upd_b1, upd_W2, upd_b2,
                                            out_force, out_disp, ln_g, ln_b, out_atom, N);
}

// Round 6
// 602.734 us; speedup vs baseline: 3.8790x; 1.0544x over previous
//
#include <hip/hip_runtime.h>
#include <hip/hip_bf16.h>

#define F 128
#define NB 20
#define HSTRIDE 136

typedef __attribute__((ext_vector_type(8))) short short8;
typedef __attribute__((ext_vector_type(4))) short short4v;
typedef __attribute__((ext_vector_type(4))) float floatx4;

__device__ __forceinline__ float silu_f(float x) {
    return x * __builtin_amdgcn_rcpf(1.0f + __expf(-x));
}

// ---------------- fused 2-layer bf16 MFMA MLP ----------------
// Y = (silu(X@W1+b1))@W2 (+ b2). A = weight tile (Wt[n][k]), B = X tile ->
// D[row=feature][col=row-of-X]: lane holds 4 contiguous features of one row
// -> packed 8B bf16 / 16B fp32 stores. Block=256=4 waves, 128 rows/block.
template<typename OUT_T, bool BIAS>
__global__ __launch_bounds__(256) void fused_mlp_kernel(
    const __hip_bfloat16* __restrict__ X,
    const __hip_bfloat16* __restrict__ Wt1, const float* __restrict__ b1,
    const __hip_bfloat16* __restrict__ Wt2, const float* __restrict__ b2,
    OUT_T* __restrict__ Y, int Mp)
{
    __shared__ __hip_bfloat16 hid[128 * HSTRIDE];
    const int t = threadIdx.x;
    const int wave = t >> 6;
    const int lane = t & 63;
    const int quad = lane >> 4;
    const int l16  = lane & 15;
    const int eloc0 = wave * 32;
    const int e0 = blockIdx.x * 128 + eloc0;

    floatx4 acc[8][2];
#pragma unroll
    for (int ft = 0; ft < 8; ++ft)
#pragma unroll
        for (int et = 0; et < 2; ++et)
            acc[ft][et] = (floatx4){0.f, 0.f, 0.f, 0.f};

#pragma unroll
    for (int ks = 0; ks < 4; ++ks) {
        const int k0 = ks * 32 + quad * 8;
        short8 bx[2], aw[8];
#pragma unroll
        for (int et = 0; et < 2; ++et)
            bx[et] = *(const short8*)(X + (size_t)(e0 + et * 16 + l16) * F + k0);
#pragma unroll
        for (int ft = 0; ft < 8; ++ft)
            aw[ft] = *(const short8*)(Wt1 + (size_t)(ft * 16 + l16) * F + k0);
#pragma unroll
        for (int ft = 0; ft < 8; ++ft)
#pragma unroll
            for (int et = 0; et < 2; ++et)
                acc[ft][et] = __builtin_amdgcn_mfma_f32_16x16x32_bf16(
                    aw[ft], bx[et], acc[ft][et], 0, 0, 0);
    }

#pragma unroll
    for (int ft = 0; ft < 8; ++ft) {
        const int feat = ft * 16 + quad * 4;
        floatx4 bv = (floatx4){0.f, 0.f, 0.f, 0.f};
        if (BIAS) bv = *(const floatx4*)(b1 + feat);
#pragma unroll
        for (int et = 0; et < 2; ++et) {
            const int el = eloc0 + et * 16 + l16;
            __align__(8) __hip_bfloat16 tmp[4];
#pragma unroll
            for (int r = 0; r < 4; ++r)
                tmp[r] = __float2bfloat16(silu_f(acc[ft][et][r] + bv[r]));
            *(short4v*)(hid + (size_t)el * HSTRIDE + feat) = *(const short4v*)tmp;
        }
    }
    __syncthreads();

#pragma unroll
    for (int ft = 0; ft < 8; ++ft)
#pragma unroll
        for (int et = 0; et < 2; ++et)
            acc[ft][et] = (floatx4){0.f, 0.f, 0.f, 0.f};

#pragma unroll
    for (int ks = 0; ks < 4; ++ks) {
        const int k0 = ks * 32 + quad * 8;
        short8 bx[2], aw[8];
#pragma unroll
        for (int et = 0; et < 2; ++et)
            bx[et] = *(const short8*)(hid + (size_t)(eloc0 + et * 16 + l16) * HSTRIDE + k0);
#pragma unroll
        for (int ft = 0; ft < 8; ++ft)
            aw[ft] = *(const short8*)(Wt2 + (size_t)(ft * 16 + l16) * F + k0);
#pragma unroll
        for (int ft = 0; ft < 8; ++ft)
#pragma unroll
            for (int et = 0; et < 2; ++et)
                acc[ft][et] = __builtin_amdgcn_mfma_f32_16x16x32_bf16(
                    aw[ft], bx[et], acc[ft][et], 0, 0, 0);
    }

#pragma unroll
    for (int ft = 0; ft < 8; ++ft) {
        const int feat = ft * 16 + quad * 4;
        floatx4 bv = (floatx4){0.f, 0.f, 0.f, 0.f};
        if (BIAS) bv = *(const floatx4*)(b2 + feat);
#pragma unroll
        for (int et = 0; et < 2; ++et) {
            const int e = e0 + et * 16 + l16;
            if (sizeof(OUT_T) == 2) {
                __align__(8) __hip_bfloat16 tmp[4];
#pragma unroll
                for (int r = 0; r < 4; ++r)
                    tmp[r] = __float2bfloat16(acc[ft][et][r] + bv[r]);
                *(short4v*)((__hip_bfloat16*)Y + (size_t)e * F + feat) = *(const short4v*)tmp;
            } else {
                floatx4 v;
#pragma unroll
                for (int r = 0; r < 4; ++r) v[r] = acc[ft][et][r] + bv[r];
                *(floatx4*)((float*)Y + (size_t)e * F + feat) = v;
            }
        }
    }
}

// Convert 10 weight matrices [k][n] fp32 -> transposed bf16 Wt[n][k].
__global__ void prep_weights_kernel(
    const float* __restrict__ W0, const float* __restrict__ W1,
    const float* __restrict__ W2, const float* __restrict__ W3,
    const float* __restrict__ W4, const float* __restrict__ W5,
    const float* __restrict__ W6, const float* __restrict__ W7,
    const float* __restrict__ W8, const float* __restrict__ W9,
    __hip_bfloat16* __restrict__ Wt)
{
    const int t = blockIdx.x * 256 + threadIdx.x;
    if (t >= 10 * F * F) return;
    const int w = t >> 14;
    const int idx = t & (F * F - 1);
    const int n = idx >> 7;
    const int k = idx & 127;
    const float* W = (w == 0) ? W0 : (w == 1) ? W1 : (w == 2) ? W2 : (w == 3) ? W3
                   : (w == 4) ? W4 : (w == 5) ? W5 : (w == 6) ? W6 : (w == 7) ? W7
                   : (w == 8) ? W8 : W9;
    Wt[t] = __float2bfloat16(W[k * F + n]);
}

__global__ void cast_pad_kernel(const float* __restrict__ src,
                                __hip_bfloat16* __restrict__ dst,
                                int n_valid, int n_total)
{
    const int stride = gridDim.x * blockDim.x;
    for (int i = blockIdx.x * blockDim.x + threadIdx.x; i < n_total; i += stride)
        dst[i] = __float2bfloat16(i < n_valid ? src[i] : 0.0f);
}

__global__ void pad_zero_bf_kernel(__hip_bfloat16* __restrict__ dst,
                                   int from, int to)
{
    const int i = from + blockIdx.x * 256 + threadIdx.x;
    if (i < to) dst[i] = __float2bfloat16(0.0f);
}

// ---------------- CSR build (edges grouped by src) ----------------

__global__ void zero_counts_kernel(int* __restrict__ counts, int N) {
    const int stride = gridDim.x * blockDim.x;
    for (int i = blockIdx.x * blockDim.x + threadIdx.x; i < N; i += stride)
        counts[i] = 0;
}

__global__ void csr_count_kernel(const int* __restrict__ src,
                                 int* __restrict__ counts, int E) {
    const int stride = gridDim.x * blockDim.x;
    for (int e = blockIdx.x * blockDim.x + threadIdx.x; e < E; e += stride)
        atomicAdd(&counts[src[e]], 1);
}

__global__ __launch_bounds__(1024) void csr_scan_kernel(
    const int* __restrict__ counts, int* __restrict__ offsets,
    int* __restrict__ cursor, int N)
{
    constexpr int T = 1024;
    const int t = threadIdx.x;
    const int per = (N + T - 1) / T;
    const int base = t * per;
    int lsum = 0;
    for (int i = 0; i < per; ++i) {
        int idx = base + i;
        if (idx < N) lsum += counts[idx];
    }
    __shared__ int s[T];
    s[t] = lsum;
    __syncthreads();
    for (int off = 1; off < T; off <<= 1) {
        int v = (t >= off) ? s[t - off] : 0;
        __syncthreads();
        s[t] += v;
        __syncthreads();
    }
    int run = s[t] - lsum;
    for (int i = 0; i < per; ++i) {
        int idx = base + i;
        if (idx < N) {
            offsets[idx] = run;
            cursor[idx] = run;
            run += counts[idx];
        }
    }
    if (t == T - 1) offsets[N] = run;
}

// perm + permuted dst + permuted disp_edge (CSR edge order everywhere)
__global__ void csr_perm_kernel(const int* __restrict__ src,
                                const int* __restrict__ dst,
                                const float* __restrict__ disp_edge,
                                int* __restrict__ cursor,
                                int* __restrict__ perm,
                                int* __restrict__ dst_p,
                                float* __restrict__ de_p, int E) {
    const int stride = gridDim.x * blockDim.x;
    for (int e = blockIdx.x * blockDim.x + threadIdx.x; e < E; e += stride) {
        int pos = atomicAdd(&cursor[src[e]], 1);
        perm[pos] = e;
        dst_p[pos] = dst[e];
        de_p[3 * pos + 0] = disp_edge[3 * e + 0];
        de_p[3 * pos + 1] = disp_edge[3 * e + 1];
        de_p[3 * pos + 2] = disp_edge[3 * e + 2];
    }
}

// ---------------- edge invariant message (CSR-ordered output) ----------------
// Xbf[p] = bf16((dist_edge[perm[p]]@emp_W + emp_b) * h[src] * h[dst])
__global__ __launch_bounds__(128) void edge_inv_kernel(
    const float* __restrict__ dist_edge, const float* __restrict__ emp_W,
    const float* __restrict__ emp_b, const __hip_bfloat16* __restrict__ h,
    const int* __restrict__ src, const int* __restrict__ dst,
    const int* __restrict__ perm,
    __hip_bfloat16* __restrict__ Xbf, int E, int Mp)
{
    constexpr int R = 16;
    const int j = threadIdx.x;
    const int p0 = blockIdx.x * R;

    int ep[R];
#pragma unroll
    for (int r = 0; r < R; ++r) {
        const int p = p0 + r;
        ep[r] = (p < E) ? perm[p] : 0;
    }

    float hs[R], hd[R];
#pragma unroll
    for (int r = 0; r < R; ++r) {
        const int p = p0 + r;
        const int s = (p < E) ? src[ep[r]] : 0;
        const int d = (p < E) ? dst[ep[r]] : 0;
        hs[r] = __bfloat162float(h[(size_t)s * F + j]);
        hd[r] = __bfloat162float(h[(size_t)d * F + j]);
    }

    float acc[R];
    const float bj = emp_b[j];
#pragma unroll
    for (int r = 0; r < R; ++r) acc[r] = bj;

    const float4* de4 = (const float4*)dist_edge;
#pragma unroll
    for (int k4 = 0; k4 < NB / 4; ++k4) {
        const float w0 = emp_W[(k4 * 4 + 0) * F + j];
        const float w1 = emp_W[(k4 * 4 + 1) * F + j];
        const float w2 = emp_W[(k4 * 4 + 2) * F + j];
        const float w3 = emp_W[(k4 * 4 + 3) * F + j];
#pragma unroll
        for (int r = 0; r < R; ++r) {
            const float4 dv = de4[(size_t)ep[r] * (NB / 4) + k4];
            acc[r] = fmaf(dv.x, w0, acc[r]);
            acc[r] = fmaf(dv.y, w1, acc[r]);
            acc[r] = fmaf(dv.z, w2, acc[r]);
            acc[r] = fmaf(dv.w, w3, acc[r]);
        }
    }

#pragma unroll
    for (int r = 0; r < R; ++r) {
        const int p = p0 + r;
        if (p < Mp) {
            const float m = (p < E) ? acc[r] * hs[r] * hd[r] : 0.0f;
            Xbf[(size_t)p * F + j] = __float2bfloat16(m);
        }
    }
}

// ---------------- per-node gathers (CSR-sequential edge rows) ----------------

__global__ __launch_bounds__(128) void gather_inv_kernel(
    const __hip_bfloat16* __restrict__ inv_msg, const int* __restrict__ offsets,
    const float* __restrict__ atom,
    float* __restrict__ atom_new, __hip_bfloat16* __restrict__ atom_new_bf, int N)
{
    const int n = blockIdx.x;
    if (n >= N) return;
    const int j = threadIdx.x;
    const int p1 = offsets[n + 1];
    float acc = 0.0f;
    for (int p = offsets[n]; p < p1; ++p)
        acc += __bfloat162float(inv_msg[(size_t)p * F + j]);
    const float v = atom[(size_t)n * F + j] + acc;
    atom_new[(size_t)n * F + j] = v;
    atom_new_bf[(size_t)n * F + j] = __float2bfloat16(v);
}

// eq1 gather + out_force + packed {bf16(disp_node), bf16(eq3i*agg1)} table
__global__ __launch_bounds__(128) void gather_eq1_kernel(
    const __hip_bfloat16* __restrict__ eqm, const float* __restrict__ de_p,
    const int* __restrict__ offsets,
    const float* __restrict__ force, const float* __restrict__ disp_node,
    const __hip_bfloat16* __restrict__ eq3i_bf,
    float* __restrict__ out_force, ushort2* __restrict__ pk, int N)
{
    const int n = blockIdx.x;
    if (n >= N) return;
    const int j = threadIdx.x;
    const int p1 = offsets[n + 1];
    float a0 = 0.0f, a1 = 0.0f, a2 = 0.0f;
    for (int p = offsets[n]; p < p1; ++p) {
        const float m = __bfloat162float(eqm[(size_t)p * F + j]);
        a0 = fmaf(m, de_p[(size_t)p * 3 + 0], a0);
        a1 = fmaf(m, de_p[(size_t)p * 3 + 1], a1);
        a2 = fmaf(m, de_p[(size_t)p * 3 + 2], a2);
    }
    const float g = __bfloat162float(eq3i_bf[(size_t)n * F + j]);
    const size_t b = (size_t)n * 3 * F + j;
    out_force[b]         = force[b] + a0;
    out_force[b + F]     = force[b + F] + a1;
    out_force[b + 2 * F] = force[b + 2 * F] + a2;
    __hip_bfloat16 d0 = __float2bfloat16(disp_node[b]);
    __hip_bfloat16 d1 = __float2bfloat16(disp_node[b + F]);
    __hip_bfloat16 d2 = __float2bfloat16(disp_node[b + 2 * F]);
    __hip_bfloat16 v0 = __float2bfloat16(g * a0);
    __hip_bfloat16 v1 = __float2bfloat16(g * a1);
    __hip_bfloat16 v2 = __float2bfloat16(g * a2);
    pk[b]         = make_ushort2(*(unsigned short*)&d0, *(unsigned short*)&v0);
    pk[b + F]     = make_ushort2(*(unsigned short*)&d1, *(unsigned short*)&v1);
    pk[b + 2 * F] = make_ushort2(*(unsigned short*)&d2, *(unsigned short*)&v2);
}

// merged eq2+eq3 gather over packed table:
// out_disp[n,k,j] = disp_node[n,k,j] + sum_p m_p * disp_bf[dst_p,k,j] + v[dst_p,k,j]
__global__ __launch_bounds__(128) void gather_eq23_kernel(
    const __hip_bfloat16* __restrict__ eqm2, const ushort2* __restrict__ pk,
    const float* __restrict__ disp_node,
    const int* __restrict__ dst_p, const int* __restrict__ offsets,
    float* __restrict__ out_disp, int N)
{
    const int n = blockIdx.x;
    if (n >= N) return;
    const int j = threadIdx.x;
    const int p1 = offsets[n + 1];
    float a0 = 0.0f, a1 = 0.0f, a2 = 0.0f;
    for (int p = offsets[n]; p < p1; ++p) {
        const int d = dst_p[p];
        const float m = __bfloat162float(eqm2[(size_t)p * F + j]);
        const ushort2 c0 = pk[(size_t)d * 3 * F + j];
        const ushort2 c1 = pk[(size_t)d * 3 * F + F + j];
        const ushort2 c2 = pk[(size_t)d * 3 * F + 2 * F + j];
        a0 += m * __bfloat162float(*(const __hip_bfloat16*)&c0.x)
                + __bfloat162float(*(const __hip_bfloat16*)&c0.y);
        a1 += m * __bfloat162float(*(const __hip_bfloat16*)&c1.x)
                + __bfloat162float(*(const __hip_bfloat16*)&c1.y);
        a2 += m * __bfloat162float(*(const __hip_bfloat16*)&c2.x)
                + __bfloat162float(*(const __hip_bfloat16*)&c2.y);
    }
    const size_t b = (size_t)n * 3 * F + j;
    out_disp[b]         = disp_node[b] + a0;
    out_disp[b + F]     = disp_node[b + F] + a1;
    out_disp[b + 2 * F] = disp_node[b + 2 * F] + a2;
}

// ---------------- final update + LN (no weight streaming) ----------------

__global__ __launch_bounds__(128) void update_ln_kernel(
    const float* __restrict__ atom_new, const float* __restrict__ upd,
    const float* __restrict__ out_force, const float* __restrict__ out_disp,
    const float* __restrict__ ln_g, const float* __restrict__ ln_b,
    float* __restrict__ out_atom, int N)
{
    const int n = blockIdx.x;
    if (n >= N) return;
    const int j = threadIdx.x;
    __shared__ float red[4];

    const float* fo = out_force + (size_t)n * (3 * F) + j;
    const float* dl = out_disp + (size_t)n * (3 * F) + j;
    const float s = -(fo[0] * dl[0] + fo[F] * dl[F] + fo[2 * F] * dl[2 * F]);
    const float y = atom_new[(size_t)n * F + j] + upd[(size_t)n * F + j] * s;

    float sy = y, syy = y * y;
#pragma unroll
    for (int m = 1; m < 64; m <<= 1) {
        sy  += __shfl_xor(sy, m);
        syy += __shfl_xor(syy, m);
    }
    if ((j & 63) == 0) {
        red[(j >> 6) * 2 + 0] = sy;
        red[(j >> 6) * 2 + 1] = syy;
    }
    __syncthreads();
    const float tsy  = red[0] + red[2];
    const float tsyy = red[1] + red[3];
    const float mu = tsy * (1.0f / F);
    float var = tsyy * (1.0f / F) - mu * mu;
    if (var < 0.0f) var = 0.0f;
    const float rstd = rsqrtf(var + 1e-5f);
    out_atom[(size_t)n * F + j] = (y - mu) * rstd * ln_g[j] + ln_b[j];
}

extern "C" void kernel_launch(void* const* d_in, const int* in_sizes, int n_in,
                              void* d_out, int out_size, void* d_ws, size_t ws_size,
                              hipStream_t stream)
{
    const float* atom_node  = (const float*)d_in[0];
    const float* force_node = (const float*)d_in[1];
    const float* disp_node  = (const float*)d_in[2];
    const float* disp_edge  = (const float*)d_in[3];
    const float* dist_edge  = (const float*)d_in[4];
    const int*   edge_index = (const int*)d_in[5];
    const float* nmp_W1 = (const float*)d_in[6];
    const float* nmp_b1 = (const float*)d_in[7];
    const float* nmp_W2 = (const float*)d_in[8];
    const float* nmp_b2 = (const float*)d_in[9];
    const float* emp_W  = (const float*)d_in[10];
    const float* emp_b  = (const float*)d_in[11];
    const float* eq1_W1 = (const float*)d_in[12];
    const float* eq1_b1 = (const float*)d_in[13];
    const float* eq1_W2 = (const float*)d_in[14];
    const float* eq1_b2 = (const float*)d_in[15];
    const float* eq2_W1 = (const float*)d_in[16];
    const float* eq2_b1 = (const float*)d_in[17];
    const float* eq2_W2 = (const float*)d_in[18];
    const float* eq2_b2 = (const float*)d_in[19];
    const float* eq3_W1 = (const float*)d_in[20];
    const float* eq3_W2 = (const float*)d_in[21];
    const float* upd_W1 = (const float*)d_in[22];
    const float* upd_b1 = (const float*)d_in[23];
    const float* upd_W2 = (const float*)d_in[24];
    const float* upd_b2 = (const float*)d_in[25];
    const float* ln_g   = (const float*)d_in[26];
    const float* ln_b   = (const float*)d_in[27];

    const int N = in_sizes[0] / F;            // 10000
    const int E = in_sizes[4] / NB;           // 200000
    const int Mp  = ((E + 127) / 128) * 128;  // 200064
    const int Mp2 = ((N + 127) / 128) * 128;  // 10112
    const int* src = edge_index;
    const int* dst = edge_index + E;
    const int nF = N * F, n3F = N * 3 * F;

    float* out_atom  = (float*)d_out;
    float* out_force = out_atom + (size_t)nF;
    float* out_disp  = out_force + (size_t)n3F;

    // ---- workspace layout ----
    char* p = (char*)d_ws;
    int* counts  = (int*)p;
    int* offsets = counts + N;
    int* cursor  = offsets + (N + 1);
    int* perm    = cursor + N;
    int* dst_p   = perm + E;
    size_t off = (size_t)(3 * N + 1 + 2 * E) * sizeof(int);
    off = (off + 63) & ~(size_t)63;
    float* de_p = (float*)(p + off); off += (size_t)3 * E * sizeof(float);
    off = (off + 63) & ~(size_t)63;

    __hip_bfloat16* h_bf        = (__hip_bfloat16*)(p + off); off += (size_t)Mp2 * F * 2;
    __hip_bfloat16* atom_bf     = (__hip_bfloat16*)(p + off); off += (size_t)Mp2 * F * 2;
    __hip_bfloat16* atom_new_bf = (__hip_bfloat16*)(p + off); off += (size_t)Mp2 * F * 2;
    __hip_bfloat16* eq3i_bf     = (__hip_bfloat16*)(p + off); off += (size_t)Mp2 * F * 2;
    off = (off + 63) & ~(size_t)63;
    float* atom_new = (float*)(p + off); off += (size_t)nF * 4;
    float* upd_f    = (float*)(p + off); off += (size_t)Mp2 * F * 4;
    ushort2* pk     = (ushort2*)(p + off); off += (size_t)n3F * sizeof(ushort2);
    off = (off + 63) & ~(size_t)63;
    __hip_bfloat16* Xbf = (__hip_bfloat16*)(p + off); off += (size_t)Mp * F * 2;
    __hip_bfloat16* Qbf = (__hip_bfloat16*)(p + off); off += (size_t)Mp * F * 2;
    __hip_bfloat16* Wt  = (__hip_bfloat16*)(p + off); // 10*F*F bf16
    __hip_bfloat16* Wt_eq1a = Wt + 0 * F * F;
    __hip_bfloat16* Wt_eq1b = Wt + 1 * F * F;
    __hip_bfloat16* Wt_eq2a = Wt + 2 * F * F;
    __hip_bfloat16* Wt_eq2b = Wt + 3 * F * F;
    __hip_bfloat16* Wt_nmpa = Wt + 4 * F * F;
    __hip_bfloat16* Wt_nmpb = Wt + 5 * F * F;
    __hip_bfloat16* Wt_eq3a = Wt + 6 * F * F;
    __hip_bfloat16* Wt_eq3b = Wt + 7 * F * F;
    __hip_bfloat16* Wt_upda = Wt + 8 * F * F;
    __hip_bfloat16* Wt_updb = Wt + 9 * F * F;

    // ---- prep: weights, casts, pads, CSR ----
    prep_weights_kernel<<<(10 * F * F + 255) / 256, 256, 0, stream>>>(
        eq1_W1, eq1_W2, eq2_W1, eq2_W2, nmp_W1, nmp_W2, eq3_W1, eq3_W2,
        upd_W1, upd_W2, Wt);
    cast_pad_kernel<<<512, 256, 0, stream>>>(atom_node, atom_bf, nF, Mp2 * F);
    pad_zero_bf_kernel<<<(Mp2 * F - nF + 255) / 256, 256, 0, stream>>>(
        atom_new_bf, nF, Mp2 * F);
    zero_counts_kernel<<<64, 256, 0, stream>>>(counts, N);
    csr_count_kernel<<<256, 256, 0, stream>>>(src, counts, E);
    csr_scan_kernel<<<1, 1024, 0, stream>>>(counts, offsets, cursor, N);
    csr_perm_kernel<<<256, 256, 0, stream>>>(src, dst, disp_edge, cursor,
                                             perm, dst_p, de_p, E);

    // ---- h = mlp2(atom_node, nmp) ----
    fused_mlp_kernel<__hip_bfloat16, true><<<Mp2 / 128, 256, 0, stream>>>(
        atom_bf, Wt_nmpa, nmp_b1, Wt_nmpb, nmp_b2, h_bf, Mp2);

    // ---- invariant message (CSR-ordered) + node aggregation ----
    edge_inv_kernel<<<Mp / 16, 128, 0, stream>>>(dist_edge, emp_W, emp_b, h_bf,
                                                 src, dst, perm, Xbf, E, Mp);
    gather_inv_kernel<<<N, 128, 0, stream>>>(Xbf, offsets, atom_node,
                                             atom_new, atom_new_bf, N);

    // ---- eq3 gate MLP (needed by gather_eq1's v computation) ----
    fused_mlp_kernel<__hip_bfloat16, false><<<Mp2 / 128, 256, 0, stream>>>(
        atom_new_bf, Wt_eq3a, nullptr, Wt_eq3b, nullptr, eq3i_bf, Mp2);

    // ---- eq1 MLP + gather (out_force, packed disp/v table) ----
    fused_mlp_kernel<__hip_bfloat16, true><<<Mp / 128, 256, 0, stream>>>(
        Xbf, Wt_eq1a, eq1_b1, Wt_eq1b, eq1_b2, Qbf, Mp);
    gather_eq1_kernel<<<N, 128, 0, stream>>>(Qbf, de_p, offsets, force_node,
                                             disp_node, eq3i_bf, out_force, pk, N);

    // ---- eq2 MLP + merged eq2+eq3 gather ----
    fused_mlp_kernel<__hip_bfloat16, true><<<Mp / 128, 256, 0, stream>>>(
        Xbf, Wt_eq2a, eq2_b1, Wt_eq2b, eq2_b2, Qbf, Mp);
    gather_eq23_kernel<<<N, 128, 0, stream>>>(Qbf, pk, disp_node, dst_p,
                                              offsets, out_disp, N);

    // ---- upd MLP (fp32 out) + final update + layernorm ----
    fused_mlp_kernel<float, true><<<Mp2 / 128, 256, 0, stream>>>(
        atom_new_bf, Wt_upda, upd_b1, Wt_updb, upd_b2, upd_f, Mp2);
    update_ln_kernel<<<N, 128, 0, stream>>>(atom_new, upd_f, out_force, out_disp,
                                            ln_g, ln_b, out_atom, N);
}

// Round 7
// 536.444 us; speedup vs baseline: 4.3583x; 1.1236x over previous
//
#include <hip/hip_runtime.h>
#include <hip/hip_bf16.h>

#define F 128
#define NB 20
#define KP 32          // padded K for the edge-embedding MFMA
#define HSTRIDE 136

typedef __attribute__((ext_vector_type(8))) short short8;
typedef __attribute__((ext_vector_type(4))) short short4v;
typedef __attribute__((ext_vector_type(4))) float floatx4;

__device__ __forceinline__ float silu_f(float x) {
    return x * __builtin_amdgcn_rcpf(1.0f + __expf(-x));
}
__device__ __forceinline__ float bfs2f(short s) {
    unsigned int u = ((unsigned int)(unsigned short)s) << 16;
    float f; __builtin_memcpy(&f, &u, 4); return f;
}

// ---------------- fused 2-layer bf16 MFMA MLP (node-level users too) --------
// Y = (silu(X@W1+b1))@W2 (+ b2). A = weight tile (Wt[n][k]), B = X tile ->
// D[row=feature][col=row-of-X]: lane holds 4 contiguous features of one row.
template<typename OUT_T, bool BIAS>
__global__ __launch_bounds__(256) void fused_mlp_kernel(
    const __hip_bfloat16* __restrict__ X,
    const __hip_bfloat16* __restrict__ Wt1, const float* __restrict__ b1,
    const __hip_bfloat16* __restrict__ Wt2, const float* __restrict__ b2,
    OUT_T* __restrict__ Y, int Mp)
{
    __shared__ __hip_bfloat16 hid[128 * HSTRIDE];
    const int t = threadIdx.x;
    const int wave = t >> 6;
    const int lane = t & 63;
    const int quad = lane >> 4;
    const int l16  = lane & 15;
    const int eloc0 = wave * 32;
    const int e0 = blockIdx.x * 128 + eloc0;

    floatx4 acc[8][2];
#pragma unroll
    for (int ft = 0; ft < 8; ++ft)
#pragma unroll
        for (int et = 0; et < 2; ++et)
            acc[ft][et] = (floatx4){0.f, 0.f, 0.f, 0.f};

#pragma unroll
    for (int ks = 0; ks < 4; ++ks) {
        const int k0 = ks * 32 + quad * 8;
        short8 bx[2], aw[8];
#pragma unroll
        for (int et = 0; et < 2; ++et)
            bx[et] = *(const short8*)(X + (size_t)(e0 + et * 16 + l16) * F + k0);
#pragma unroll
        for (int ft = 0; ft < 8; ++ft)
            aw[ft] = *(const short8*)(Wt1 + (size_t)(ft * 16 + l16) * F + k0);
#pragma unroll
        for (int ft = 0; ft < 8; ++ft)
#pragma unroll
            for (int et = 0; et < 2; ++et)
                acc[ft][et] = __builtin_amdgcn_mfma_f32_16x16x32_bf16(
                    aw[ft], bx[et], acc[ft][et], 0, 0, 0);
    }

#pragma unroll
    for (int ft = 0; ft < 8; ++ft) {
        const int feat = ft * 16 + quad * 4;
        floatx4 bv = (floatx4){0.f, 0.f, 0.f, 0.f};
        if (BIAS) bv = *(const floatx4*)(b1 + feat);
#pragma unroll
        for (int et = 0; et < 2; ++et) {
            const int el = eloc0 + et * 16 + l16;
            __align__(8) __hip_bfloat16 tmp[4];
#pragma unroll
            for (int r = 0; r < 4; ++r)
                tmp[r] = __float2bfloat16(silu_f(acc[ft][et][r] + bv[r]));
            *(short4v*)(hid + (size_t)el * HSTRIDE + feat) = *(const short4v*)tmp;
        }
    }
    __syncthreads();

#pragma unroll
    for (int ft = 0; ft < 8; ++ft)
#pragma unroll
        for (int et = 0; et < 2; ++et)
            acc[ft][et] = (floatx4){0.f, 0.f, 0.f, 0.f};

#pragma unroll
    for (int ks = 0; ks < 4; ++ks) {
        const int k0 = ks * 32 + quad * 8;
        short8 bx[2], aw[8];
#pragma unroll
        for (int et = 0; et < 2; ++et)
            bx[et] = *(const short8*)(hid + (size_t)(eloc0 + et * 16 + l16) * HSTRIDE + k0);
#pragma unroll
        for (int ft = 0; ft < 8; ++ft)
            aw[ft] = *(const short8*)(Wt2 + (size_t)(ft * 16 + l16) * F + k0);
#pragma unroll
        for (int ft = 0; ft < 8; ++ft)
#pragma unroll
            for (int et = 0; et < 2; ++et)
                acc[ft][et] = __builtin_amdgcn_mfma_f32_16x16x32_bf16(
                    aw[ft], bx[et], acc[ft][et], 0, 0, 0);
    }

#pragma unroll
    for (int ft = 0; ft < 8; ++ft) {
        const int feat = ft * 16 + quad * 4;
        floatx4 bv = (floatx4){0.f, 0.f, 0.f, 0.f};
        if (BIAS) bv = *(const floatx4*)(b2 + feat);
#pragma unroll
        for (int et = 0; et < 2; ++et) {
            const int e = e0 + et * 16 + l16;
            if (sizeof(OUT_T) == 2) {
                __align__(8) __hip_bfloat16 tmp[4];
#pragma unroll
                for (int r = 0; r < 4; ++r)
                    tmp[r] = __float2bfloat16(acc[ft][et][r] + bv[r]);
                *(short4v*)((__hip_bfloat16*)Y + (size_t)e * F + feat) = *(const short4v*)tmp;
            } else {
                floatx4 v;
#pragma unroll
                for (int r = 0; r < 4; ++r) v[r] = acc[ft][et][r] + bv[r];
                *(floatx4*)((float*)Y + (size_t)e * F + feat) = v;
            }
        }
    }
}

// ---------------- dual fused MLP: eq1 + eq2 in one pass over X --------------
// X fragments held in registers across both MLPs (halves X traffic).
// Q2 may alias X (each block reads its own X rows before writing Q2 rows),
// so X/Q2 carry no __restrict__.
__global__ __launch_bounds__(256) void dual_mlp_kernel(
    const __hip_bfloat16* X,
    const __hip_bfloat16* __restrict__ W1a, const float* __restrict__ b1a,
    const __hip_bfloat16* __restrict__ W2a, const float* __restrict__ b2a,
    const __hip_bfloat16* __restrict__ W1b, const float* __restrict__ b1b,
    const __hip_bfloat16* __restrict__ W2b, const float* __restrict__ b2b,
    __hip_bfloat16* __restrict__ Q1, __hip_bfloat16* Q2, int Mp)
{
    __shared__ __hip_bfloat16 hid[128 * HSTRIDE];
    const int t = threadIdx.x;
    const int wave = t >> 6;
    const int lane = t & 63;
    const int quad = lane >> 4;
    const int l16  = lane & 15;
    const int eloc0 = wave * 32;
    const int e0 = blockIdx.x * 128 + eloc0;

    // hold all X fragments (4 ks x 2 et x 16B = 32 VGPR)
    short8 bxk[4][2];
#pragma unroll
    for (int ks = 0; ks < 4; ++ks)
#pragma unroll
        for (int et = 0; et < 2; ++et)
            bxk[ks][et] = *(const short8*)(X + (size_t)(e0 + et * 16 + l16) * F
                                           + ks * 32 + quad * 8);

    floatx4 acc[8][2];

    // ===== MLP A (eq1) =====
#pragma unroll
    for (int ft = 0; ft < 8; ++ft)
#pragma unroll
        for (int et = 0; et < 2; ++et)
            acc[ft][et] = (floatx4){0.f, 0.f, 0.f, 0.f};
#pragma unroll
    for (int ks = 0; ks < 4; ++ks) {
        const int k0 = ks * 32 + quad * 8;
        short8 aw[8];
#pragma unroll
        for (int ft = 0; ft < 8; ++ft)
            aw[ft] = *(const short8*)(W1a + (size_t)(ft * 16 + l16) * F + k0);
#pragma unroll
        for (int ft = 0; ft < 8; ++ft)
#pragma unroll
            for (int et = 0; et < 2; ++et)
                acc[ft][et] = __builtin_amdgcn_mfma_f32_16x16x32_bf16(
                    aw[ft], bxk[ks][et], acc[ft][et], 0, 0, 0);
    }
#pragma unroll
    for (int ft = 0; ft < 8; ++ft) {
        const int feat = ft * 16 + quad * 4;
        const floatx4 bv = *(const floatx4*)(b1a + feat);
#pragma unroll
        for (int et = 0; et < 2; ++et) {
            const int el = eloc0 + et * 16 + l16;
            __align__(8) __hip_bfloat16 tmp[4];
#pragma unroll
            for (int r = 0; r < 4; ++r)
                tmp[r] = __float2bfloat16(silu_f(acc[ft][et][r] + bv[r]));
            *(short4v*)(hid + (size_t)el * HSTRIDE + feat) = *(const short4v*)tmp;
        }
    }
    __syncthreads();
#pragma unroll
    for (int ft = 0; ft < 8; ++ft)
#pragma unroll
        for (int et = 0; et < 2; ++et)
            acc[ft][et] = (floatx4){0.f, 0.f, 0.f, 0.f};
#pragma unroll
    for (int ks = 0; ks < 4; ++ks) {
        const int k0 = ks * 32 + quad * 8;
        short8 bh[2], aw[8];
#pragma unroll
        for (int et = 0; et < 2; ++et)
            bh[et] = *(const short8*)(hid + (size_t)(eloc0 + et * 16 + l16) * HSTRIDE + k0);
#pragma unroll
        for (int ft = 0; ft < 8; ++ft)
            aw[ft] = *(const short8*)(W2a + (size_t)(ft * 16 + l16) * F + k0);
#pragma unroll
        for (int ft = 0; ft < 8; ++ft)
#pragma unroll
            for (int et = 0; et < 2; ++et)
                acc[ft][et] = __builtin_amdgcn_mfma_f32_16x16x32_bf16(
                    aw[ft], bh[et], acc[ft][et], 0, 0, 0);
    }
#pragma unroll
    for (int ft = 0; ft < 8; ++ft) {
        const int feat = ft * 16 + quad * 4;
        const floatx4 bv = *(const floatx4*)(b2a + feat);
#pragma unroll
        for (int et = 0; et < 2; ++et) {
            const int e = e0 + et * 16 + l16;
            __align__(8) __hip_bfloat16 tmp[4];
#pragma unroll
            for (int r = 0; r < 4; ++r)
                tmp[r] = __float2bfloat16(acc[ft][et][r] + bv[r]);
            *(short4v*)(Q1 + (size_t)e * F + feat) = *(const short4v*)tmp;
        }
    }

    // ===== MLP B (eq2), reusing bxk =====
#pragma unroll
    for (int ft = 0; ft < 8; ++ft)
#pragma unroll
        for (int et = 0; et < 2; ++et)
            acc[ft][et] = (floatx4){0.f, 0.f, 0.f, 0.f};
#pragma unroll
    for (int ks = 0; ks < 4; ++ks) {
        const int k0 = ks * 32 + quad * 8;
        short8 aw[8];
#pragma unroll
        for (int ft = 0; ft < 8; ++ft)
            aw[ft] = *(const short8*)(W1b + (size_t)(ft * 16 + l16) * F + k0);
#pragma unroll
        for (int ft = 0; ft < 8; ++ft)
#pragma unroll
            for (int et = 0; et < 2; ++et)
                acc[ft][et] = __builtin_amdgcn_mfma_f32_16x16x32_bf16(
                    aw[ft], bxk[ks][et], acc[ft][et], 0, 0, 0);
    }
    __syncthreads();   // all waves done reading hid (MLP A layer 2)
#pragma unroll
    for (int ft = 0; ft < 8; ++ft) {
        const int feat = ft * 16 + quad * 4;
        const floatx4 bv = *(const floatx4*)(b1b + feat);
#pragma unroll
        for (int et = 0; et < 2; ++et) {
            const int el = eloc0 + et * 16 + l16;
            __align__(8) __hip_bfloat16 tmp[4];
#pragma unroll
            for (int r = 0; r < 4; ++r)
                tmp[r] = __float2bfloat16(silu_f(acc[ft][et][r] + bv[r]));
            *(short4v*)(hid + (size_t)el * HSTRIDE + feat) = *(const short4v*)tmp;
        }
    }
    __syncthreads();
#pragma unroll
    for (int ft = 0; ft < 8; ++ft)
#pragma unroll
        for (int et = 0; et < 2; ++et)
            acc[ft][et] = (floatx4){0.f, 0.f, 0.f, 0.f};
#pragma unroll
    for (int ks = 0; ks < 4; ++ks) {
        const int k0 = ks * 32 + quad * 8;
        short8 bh[2], aw[8];
#pragma unroll
        for (int et = 0; et < 2; ++et)
            bh[et] = *(const short8*)(hid + (size_t)(eloc0 + et * 16 + l16) * HSTRIDE + k0);
#pragma unroll
        for (int ft = 0; ft < 8; ++ft)
            aw[ft] = *(const short8*)(W2b + (size_t)(ft * 16 + l16) * F + k0);
#pragma unroll
        for (int ft = 0; ft < 8; ++ft)
#pragma unroll
            for (int et = 0; et < 2; ++et)
                acc[ft][et] = __builtin_amdgcn_mfma_f32_16x16x32_bf16(
                    aw[ft], bh[et], acc[ft][et], 0, 0, 0);
    }
#pragma unroll
    for (int ft = 0; ft < 8; ++ft) {
        const int feat = ft * 16 + quad * 4;
        const floatx4 bv = *(const floatx4*)(b2b + feat);
#pragma unroll
        for (int et = 0; et < 2; ++et) {
            const int e = e0 + et * 16 + l16;
            __align__(8) __hip_bfloat16 tmp[4];
#pragma unroll
            for (int r = 0; r < 4; ++r)
                tmp[r] = __float2bfloat16(acc[ft][et][r] + bv[r]);
            *(short4v*)(Q2 + (size_t)e * F + feat) = *(const short4v*)tmp;
        }
    }
}

// ---------------- edge invariant message: K=32 MFMA + gathered h products ---
// Xbf[p] = bf16((dist_p[p] @ emp_W + emp_b) * h[src_p[p]] * h[dst_p[p]])
__global__ __launch_bounds__(256) void edge_inv_mfma_kernel(
    const __hip_bfloat16* __restrict__ dist_p,
    const __hip_bfloat16* __restrict__ empWt,   // [128 feat][32 k]
    const float* __restrict__ emp_b, const __hip_bfloat16* __restrict__ h,
    const int* __restrict__ src_p, const int* __restrict__ dst_p,
    __hip_bfloat16* __restrict__ Xbf, int E)
{
    const int t = threadIdx.x;
    const int wave = t >> 6;
    const int lane = t & 63;
    const int quad = lane >> 4;
    const int l16  = lane & 15;
    const int e0 = blockIdx.x * 128 + wave * 32;

    short8 bx[2], aw[8];
#pragma unroll
    for (int et = 0; et < 2; ++et)
        bx[et] = *(const short8*)(dist_p + (size_t)(e0 + et * 16 + l16) * KP + quad * 8);
#pragma unroll
    for (int ft = 0; ft < 8; ++ft)
        aw[ft] = *(const short8*)(empWt + (size_t)(ft * 16 + l16) * KP + quad * 8);

    floatx4 acc[8][2];
#pragma unroll
    for (int ft = 0; ft < 8; ++ft)
#pragma unroll
        for (int et = 0; et < 2; ++et)
            acc[ft][et] = __builtin_amdgcn_mfma_f32_16x16x32_bf16(
                aw[ft], bx[et], (floatx4){0.f, 0.f, 0.f, 0.f}, 0, 0, 0);

    int eidx[2], sR[2], dR[2];
#pragma unroll
    for (int et = 0; et < 2; ++et) {
        eidx[et] = e0 + et * 16 + l16;
        const bool v = eidx[et] < E;
        sR[et] = v ? src_p[eidx[et]] : 0;
        dR[et] = v ? dst_p[eidx[et]] : 0;
    }

#pragma unroll
    for (int ft = 0; ft < 8; ++ft) {
        const int feat = ft * 16 + quad * 4;
        const floatx4 bv = *(const floatx4*)(emp_b + feat);
#pragma unroll
        for (int et = 0; et < 2; ++et) {
            const short4v hs = *(const short4v*)(h + (size_t)sR[et] * F + feat);
            const short4v hd = *(const short4v*)(h + (size_t)dR[et] * F + feat);
            const bool v = eidx[et] < E;
            __align__(8) __hip_bfloat16 tmp[4];
#pragma unroll
            for (int r = 0; r < 4; ++r) {
                const float m = v ? (acc[ft][et][r] + bv[r]) * bfs2f(hs[r]) * bfs2f(hd[r])
                                  : 0.0f;
                tmp[r] = __float2bfloat16(m);
            }
            *(short4v*)(Xbf + (size_t)eidx[et] * F + feat) = *(const short4v*)tmp;
        }
    }
}

// ---------------- weight prep ----------------

__global__ void prep_weights_kernel(
    const float* __restrict__ W0, const float* __restrict__ W1,
    const float* __restrict__ W2, const float* __restrict__ W3,
    const float* __restrict__ W4, const float* __restrict__ W5,
    const float* __restrict__ W6, const float* __restrict__ W7,
    const float* __restrict__ W8, const float* __restrict__ W9,
    __hip_bfloat16* __restrict__ Wt)
{
    const int t = blockIdx.x * 256 + threadIdx.x;
    if (t >= 10 * F * F) return;
    const int w = t >> 14;
    const int idx = t & (F * F - 1);
    const int n = idx >> 7;
    const int k = idx & 127;
    const float* W = (w == 0) ? W0 : (w == 1) ? W1 : (w == 2) ? W2 : (w == 3) ? W3
                   : (w == 4) ? W4 : (w == 5) ? W5 : (w == 6) ? W6 : (w == 7) ? W7
                   : (w == 8) ? W8 : W9;
    Wt[t] = __float2bfloat16(W[k * F + n]);
}

// emp_W [NB][F] fp32 -> empWt [F][KP] bf16, zero-padded k in [NB,KP)
__global__ void prep_empw_kernel(const float* __restrict__ emp_W,
                                 __hip_bfloat16* __restrict__ empWt)
{
    const int t = blockIdx.x * 256 + threadIdx.x;
    if (t >= F * KP) return;
    const int n = t >> 5;
    const int k = t & (KP - 1);
    empWt[t] = __float2bfloat16(k < NB ? emp_W[k * F + n] : 0.0f);
}

__global__ void cast_pad_kernel(const float* __restrict__ src,
                                __hip_bfloat16* __restrict__ dst,
                                int n_valid, int n_total)
{
    const int stride = gridDim.x * blockDim.x;
    for (int i = blockIdx.x * blockDim.x + threadIdx.x; i < n_total; i += stride)
        dst[i] = __float2bfloat16(i < n_valid ? src[i] : 0.0f);
}

__global__ void pad_zero_bf_kernel(__hip_bfloat16* __restrict__ dst,
                                   int from, int to)
{
    const int i = from + blockIdx.x * 256 + threadIdx.x;
    if (i < to) dst[i] = __float2bfloat16(0.0f);
}

// ---------------- CSR build (edges grouped by src) ----------------

__global__ void zero_counts_kernel(int* __restrict__ counts, int N) {
    const int stride = gridDim.x * blockDim.x;
    for (int i = blockIdx.x * blockDim.x + threadIdx.x; i < N; i += stride)
        counts[i] = 0;
}

__global__ void csr_count_kernel(const int* __restrict__ src,
                                 int* __restrict__ counts, int E) {
    const int stride = gridDim.x * blockDim.x;
    for (int e = blockIdx.x * blockDim.x + threadIdx.x; e < E; e += stride)
        atomicAdd(&counts[src[e]], 1);
}

__global__ __launch_bounds__(1024) void csr_scan_kernel(
    const int* __restrict__ counts, int* __restrict__ offsets,
    int* __restrict__ cursor, int N)
{
    constexpr int T = 1024;
    const int t = threadIdx.x;
    const int per = (N + T - 1) / T;
    const int base = t * per;
    int lsum = 0;
    for (int i = 0; i < per; ++i) {
        int idx = base + i;
        if (idx < N) lsum += counts[idx];
    }
    __shared__ int s[T];
    s[t] = lsum;
    __syncthreads();
    for (int off = 1; off < T; off <<= 1) {
        int v = (t >= off) ? s[t - off] : 0;
        __syncthreads();
        s[t] += v;
        __syncthreads();
    }
    int run = s[t] - lsum;
    for (int i = 0; i < per; ++i) {
        int idx = base + i;
        if (idx < N) {
            offsets[idx] = run;
            cursor[idx] = run;
            run += counts[idx];
        }
    }
    if (t == T - 1) offsets[N] = run;
}

// permute everything edge-indexed into CSR order (no perm array survives)
__global__ void csr_perm_kernel(const int* __restrict__ src,
                                const int* __restrict__ dst,
                                const float* __restrict__ disp_edge,
                                const float* __restrict__ dist_edge,
                                int* __restrict__ cursor,
                                int* __restrict__ src_p,
                                int* __restrict__ dst_p,
                                float* __restrict__ de_p,
                                __hip_bfloat16* __restrict__ dist_p, int E) {
    const int stride = gridDim.x * blockDim.x;
    for (int e = blockIdx.x * blockDim.x + threadIdx.x; e < E; e += stride) {
        const int s = src[e];
        const int pos = atomicAdd(&cursor[s], 1);
        src_p[pos] = s;
        dst_p[pos] = dst[e];
        de_p[3 * pos + 0] = disp_edge[3 * e + 0];
        de_p[3 * pos + 1] = disp_edge[3 * e + 1];
        de_p[3 * pos + 2] = disp_edge[3 * e + 2];
        __align__(16) __hip_bfloat16 tmp[KP];
#pragma unroll
        for (int k = 0; k < KP; ++k)
            tmp[k] = __float2bfloat16(k < NB ? dist_edge[(size_t)e * NB + k] : 0.0f);
#pragma unroll
        for (int q = 0; q < 4; ++q)
            *(short8*)(dist_p + (size_t)pos * KP + q * 8) = ((const short8*)tmp)[q];
    }
}

// ---------------- per-node gathers (CSR-sequential edge rows) ----------------

__global__ __launch_bounds__(128) void gather_inv_kernel(
    const __hip_bfloat16* __restrict__ inv_msg, const int* __restrict__ offsets,
    const float* __restrict__ atom,
    float* __restrict__ atom_new, __hip_bfloat16* __restrict__ atom_new_bf, int N)
{
    const int n = blockIdx.x;
    if (n >= N) return;
    const int j = threadIdx.x;
    const int p1 = offsets[n + 1];
    float acc = 0.0f;
    for (int p = offsets[n]; p < p1; ++p)
        acc += __bfloat162float(inv_msg[(size_t)p * F + j]);
    const float v = atom[(size_t)n * F + j] + acc;
    atom_new[(size_t)n * F + j] = v;
    atom_new_bf[(size_t)n * F + j] = __float2bfloat16(v);
}

// eq1 gather + out_force + packed {bf16(disp_node), bf16(eq3i*agg1)} table
__global__ __launch_bounds__(128) void gather_eq1_kernel(
    const __hip_bfloat16* __restrict__ eqm, const float* __restrict__ de_p,
    const int* __restrict__ offsets,
    const float* __restrict__ force, const float* __restrict__ disp_node,
    const __hip_bfloat16* __restrict__ eq3i_bf,
    float* __restrict__ out_force, ushort2* __restrict__ pk, int N)
{
    const int n = blockIdx.x;
    if (n >= N) return;
    const int j = threadIdx.x;
    const int p1 = offsets[n + 1];
    float a0 = 0.0f, a1 = 0.0f, a2 = 0.0f;
    for (int p = offsets[n]; p < p1; ++p) {
        const float m = __bfloat162float(eqm[(size_t)p * F + j]);
        a0 = fmaf(m, de_p[(size_t)p * 3 + 0], a0);
        a1 = fmaf(m, de_p[(size_t)p * 3 + 1], a1);
        a2 = fmaf(m, de_p[(size_t)p * 3 + 2], a2);
    }
    const float g = __bfloat162float(eq3i_bf[(size_t)n * F + j]);
    const size_t b = (size_t)n * 3 * F + j;
    out_force[b]         = force[b] + a0;
    out_force[b + F]     = force[b + F] + a1;
    out_force[b + 2 * F] = force[b + 2 * F] + a2;
    __hip_bfloat16 d0 = __float2bfloat16(disp_node[b]);
    __hip_bfloat16 d1 = __float2bfloat16(disp_node[b + F]);
    __hip_bfloat16 d2 = __float2bfloat16(disp_node[b + 2 * F]);
    __hip_bfloat16 v0 = __float2bfloat16(g * a0);
    __hip_bfloat16 v1 = __float2bfloat16(g * a1);
    __hip_bfloat16 v2 = __float2bfloat16(g * a2);
    pk[b]         = make_ushort2(*(unsigned short*)&d0, *(unsigned short*)&v0);
    pk[b + F]     = make_ushort2(*(unsigned short*)&d1, *(unsigned short*)&v1);
    pk[b + 2 * F] = make_ushort2(*(unsigned short*)&d2, *(unsigned short*)&v2);
}

// merged eq2+eq3 gather over packed table
__global__ __launch_bounds__(128) void gather_eq23_kernel(
    const __hip_bfloat16* __restrict__ eqm2, const ushort2* __restrict__ pk,
    const float* __restrict__ disp_node,
    const int* __restrict__ dst_p, const int* __restrict__ offsets,
    float* __restrict__ out_disp, int N)
{
    const int n = blockIdx.x;
    if (n >= N) return;
    const int j = threadIdx.x;
    const int p1 = offsets[n + 1];
    float a0 = 0.0f, a1 = 0.0f, a2 = 0.0f;
    for (int p = offsets[n]; p < p1; ++p) {
        const int d = dst_p[p];
        const float m = __bfloat162float(eqm2[(size_t)p * F + j]);
        const ushort2 c0 = pk[(size_t)d * 3 * F + j];
        const ushort2 c1 = pk[(size_t)d * 3 * F + F + j];
        const ushort2 c2 = pk[(size_t)d * 3 * F + 2 * F + j];
        a0 += m * bfs2f((short)c0.x) + bfs2f((short)c0.y);
        a1 += m * bfs2f((short)c1.x) + bfs2f((short)c1.y);
        a2 += m * bfs2f((short)c2.x) + bfs2f((short)c2.y);
    }
    const size_t b = (size_t)n * 3 * F + j;
    out_disp[b]         = disp_node[b] + a0;
    out_disp[b + F]     = disp_node[b + F] + a1;
    out_disp[b + 2 * F] = disp_node[b + 2 * F] + a2;
}

// ---------------- final update + LN ----------------

__global__ __launch_bounds__(128) void update_ln_kernel(
    const float* __restrict__ atom_new, const float* __restrict__ upd,
    const float* __restrict__ out_force, const float* __restrict__ out_disp,
    const float* __restrict__ ln_g, const float* __restrict__ ln_b,
    float* __restrict__ out_atom, int N)
{
    const int n = blockIdx.x;
    if (n >= N) return;
    const int j = threadIdx.x;
    __shared__ float red[4];

    const float* fo = out_force + (size_t)n * (3 * F) + j;
    const float* dl = out_disp + (size_t)n * (3 * F) + j;
    const float s = -(fo[0] * dl[0] + fo[F] * dl[F] + fo[2 * F] * dl[2 * F]);
    const float y = atom_new[(size_t)n * F + j] + upd[(size_t)n * F + j] * s;

    float sy = y, syy = y * y;
#pragma unroll
    for (int m = 1; m < 64; m <<= 1) {
        sy  += __shfl_xor(sy, m);
        syy += __shfl_xor(syy, m);
    }
    if ((j & 63) == 0) {
        red[(j >> 6) * 2 + 0] = sy;
        red[(j >> 6) * 2 + 1] = syy;
    }
    __syncthreads();
    const float tsy  = red[0] + red[2];
    const float tsyy = red[1] + red[3];
    const float mu = tsy * (1.0f / F);
    float var = tsyy * (1.0f / F) - mu * mu;
    if (var < 0.0f) var = 0.0f;
    const float rstd = rsqrtf(var + 1e-5f);
    out_atom[(size_t)n * F + j] = (y - mu) * rstd * ln_g[j] + ln_b[j];
}

extern "C" void kernel_launch(void* const* d_in, const int* in_sizes, int n_in,
                              void* d_out, int out_size, void* d_ws, size_t ws_size,
                              hipStream_t stream)
{
    const float* atom_node  = (const float*)d_in[0];
    const float* force_node = (const float*)d_in[1];
    const float* disp_node  = (const float*)d_in[2];
    const float* disp_edge  = (const float*)d_in[3];
    const float* dist_edge  = (const float*)d_in[4];
    const int*   edge_index = (const int*)d_in[5];
    const float* nmp_W1 = (const float*)d_in[6];
    const float* nmp_b1 = (const float*)d_in[7];
    const float* nmp_W2 = (const float*)d_in[8];
    const float* nmp_b2 = (const float*)d_in[9];
    const float* emp_W  = (const float*)d_in[10];
    const float* emp_b  = (const float*)d_in[11];
    const float* eq1_W1 = (const float*)d_in[12];
    const float* eq1_b1 = (const float*)d_in[13];
    const float* eq1_W2 = (const float*)d_in[14];
    const float* eq1_b2 = (const float*)d_in[15];
    const float* eq2_W1 = (const float*)d_in[16];
    const float* eq2_b1 = (const float*)d_in[17];
    const float* eq2_W2 = (const float*)d_in[18];
    const float* eq2_b2 = (const float*)d_in[19];
    const float* eq3_W1 = (const float*)d_in[20];
    const float* eq3_W2 = (const float*)d_in[21];
    const float* upd_W1 = (const float*)d_in[22];
    const float* upd_b1 = (const float*)d_in[23];
    const float* upd_W2 = (const float*)d_in[24];
    const float* upd_b2 = (const float*)d_in[25];
    const float* ln_g   = (const float*)d_in[26];
    const float* ln_b   = (const float*)d_in[27];

    const int N = in_sizes[0] / F;            // 10000
    const int E = in_sizes[4] / NB;           // 200000
    const int Mp  = ((E + 127) / 128) * 128;  // 200064
    const int Mp2 = ((N + 127) / 128) * 128;  // 10112
    const int* src = edge_index;
    const int* dst = edge_index + E;
    const int nF = N * F, n3F = N * 3 * F;

    float* out_atom  = (float*)d_out;
    float* out_force = out_atom + (size_t)nF;
    float* out_disp  = out_force + (size_t)n3F;

    // ---- workspace layout ----
    char* p = (char*)d_ws;
    int* counts  = (int*)p;
    int* offsets = counts + N;
    int* cursor  = offsets + (N + 1);
    int* src_p   = cursor + N;
    int* dst_p   = src_p + E;
    size_t off = (size_t)(3 * N + 1 + 2 * E) * sizeof(int);
    off = (off + 63) & ~(size_t)63;
    float* de_p = (float*)(p + off); off += (size_t)3 * E * sizeof(float);
    off = (off + 63) & ~(size_t)63;
    __hip_bfloat16* dist_p = (__hip_bfloat16*)(p + off); off += (size_t)Mp * KP * 2;
    __hip_bfloat16* empWt  = (__hip_bfloat16*)(p + off); off += (size_t)F * KP * 2;

    __hip_bfloat16* h_bf        = (__hip_bfloat16*)(p + off); off += (size_t)Mp2 * F * 2;
    __hip_bfloat16* atom_bf     = (__hip_bfloat16*)(p + off); off += (size_t)Mp2 * F * 2;
    __hip_bfloat16* atom_new_bf = (__hip_bfloat16*)(p + off); off += (size_t)Mp2 * F * 2;
    __hip_bfloat16* eq3i_bf     = (__hip_bfloat16*)(p + off); off += (size_t)Mp2 * F * 2;
    off = (off + 63) & ~(size_t)63;
    float* atom_new = (float*)(p + off); off += (size_t)nF * 4;
    float* upd_f    = (float*)(p + off); off += (size_t)Mp2 * F * 4;
    ushort2* pk     = (ushort2*)(p + off); off += (size_t)n3F * sizeof(ushort2);
    off = (off + 63) & ~(size_t)63;
    __hip_bfloat16* Xbf = (__hip_bfloat16*)(p + off); off += (size_t)Mp * F * 2;
    __hip_bfloat16* Q1  = (__hip_bfloat16*)(p + off); off += (size_t)Mp * F * 2;
    __hip_bfloat16* Q2  = Xbf;   // alias: dual_mlp reads its X rows before writing Q2 rows
    __hip_bfloat16* Wt  = (__hip_bfloat16*)(p + off); // 10*F*F bf16
    __hip_bfloat16* Wt_eq1a = Wt + 0 * F * F;
    __hip_bfloat16* Wt_eq1b = Wt + 1 * F * F;
    __hip_bfloat16* Wt_eq2a = Wt + 2 * F * F;
    __hip_bfloat16* Wt_eq2b = Wt + 3 * F * F;
    __hip_bfloat16* Wt_nmpa = Wt + 4 * F * F;
    __hip_bfloat16* Wt_nmpb = Wt + 5 * F * F;
    __hip_bfloat16* Wt_eq3a = Wt + 6 * F * F;
    __hip_bfloat16* Wt_eq3b = Wt + 7 * F * F;
    __hip_bfloat16* Wt_upda = Wt + 8 * F * F;
    __hip_bfloat16* Wt_updb = Wt + 9 * F * F;

    // ---- prep: weights, casts, pads, CSR ----
    prep_weights_kernel<<<(10 * F * F + 255) / 256, 256, 0, stream>>>(
        eq1_W1, eq1_W2, eq2_W1, eq2_W2, nmp_W1, nmp_W2, eq3_W1, eq3_W2,
        upd_W1, upd_W2, Wt);
    prep_empw_kernel<<<(F * KP + 255) / 256, 256, 0, stream>>>(emp_W, empWt);
    cast_pad_kernel<<<512, 256, 0, stream>>>(atom_node, atom_bf, nF, Mp2 * F);
    pad_zero_bf_kernel<<<(Mp2 * F - nF + 255) / 256, 256, 0, stream>>>(
        atom_new_bf, nF, Mp2 * F);
    zero_counts_kernel<<<64, 256, 0, stream>>>(counts, N);
    csr_count_kernel<<<256, 256, 0, stream>>>(src, counts, E);
    csr_scan_kernel<<<1, 1024, 0, stream>>>(counts, offsets, cursor, N);
    csr_perm_kernel<<<256, 256, 0, stream>>>(src, dst, disp_edge, dist_edge,
                                             cursor, src_p, dst_p, de_p, dist_p, E);

    // ---- h = mlp2(atom_node, nmp) ----
    fused_mlp_kernel<__hip_bfloat16, true><<<Mp2 / 128, 256, 0, stream>>>(
        atom_bf, Wt_nmpa, nmp_b1, Wt_nmpb, nmp_b2, h_bf, Mp2);

    // ---- invariant message (MFMA + gathered h products) + node aggregation ----
    edge_inv_mfma_kernel<<<Mp / 128, 256, 0, stream>>>(
        dist_p, empWt, emp_b, h_bf, src_p, dst_p, Xbf, E);
    gather_inv_kernel<<<N, 128, 0, stream>>>(Xbf, offsets, atom_node,
                                             atom_new, atom_new_bf, N);

    // ---- eq3 gate MLP (needed by gather_eq1's v computation) ----
    fused_mlp_kernel<__hip_bfloat16, false><<<Mp2 / 128, 256, 0, stream>>>(
        atom_new_bf, Wt_eq3a, nullptr, Wt_eq3b, nullptr, eq3i_bf, Mp2);

    // ---- dual eq1+eq2 MLP (one pass over Xbf; Q2 aliases Xbf) ----
    dual_mlp_kernel<<<Mp / 128, 256, 0, stream>>>(
        Xbf, Wt_eq1a, eq1_b1, Wt_eq1b, eq1_b2,
        Wt_eq2a, eq2_b1, Wt_eq2b, eq2_b2, Q1, Q2, Mp);

    // ---- gathers ----
    gather_eq1_kernel<<<N, 128, 0, stream>>>(Q1, de_p, offsets, force_node,
                                             disp_node, eq3i_bf, out_force, pk, N);
    gather_eq23_kernel<<<N, 128, 0, stream>>>(Q2, pk, disp_node, dst_p,
                                              offsets, out_disp, N);

    // ---- upd MLP (fp32 out) + final update + layernorm ----
    fused_mlp_kernel<float, true><<<Mp2 / 128, 256, 0, stream>>>(
        atom_new_bf, Wt_upda, upd_b1, Wt_updb, upd_b2, upd_f, Mp2);
    update_ln_kernel<<<N, 128, 0, stream>>>(atom_new, upd_f, out_force, out_disp,
                                            ln_g, ln_b, out_atom, N);
}